// Round 6
// baseline (216.871 us; speedup 1.0000x reference)
//
#include <hip/hip_runtime.h>
#include <hip/hip_bf16.h>

typedef __hip_bfloat16 bf16;
typedef __attribute__((ext_vector_type(8))) short  bfrag;   // 8 bf16 (4 VGPR) MFMA A/B frag
typedef __attribute__((ext_vector_type(4))) float  facc;    // MFMA C/D frag
typedef __attribute__((ext_vector_type(4))) short  short4v; // 4 bf16 = 8B packed store

#define B_   8
#define T_   1024
#define C_   768
#define H_   12
#define HD_  64
#define M_   (B_ * T_)   // 8192
#define N3_  (3 * C_)    // 2304
#define NFK_ 24          // K-dim fragments: 768/32

// Q is stored pre-scaled by 0.125*log2(e) so flash softmax is p = exp2(s - M2)
#define QSCALE_ 0.18033688011112042f
#define M2_     17.312340490667562f

__device__ __forceinline__ float fexp2(float x) { return __builtin_amdgcn_exp2f(x); }

__device__ __forceinline__ void gload_lds16(const bf16* g, bf16* l) {
    __builtin_amdgcn_global_load_lds((const __attribute__((address_space(1))) void*)g,
                                     (__attribute__((address_space(3))) void*)l, 16, 0, 0);
}
__device__ __forceinline__ short bfbits(float f) {
    bf16 b = __float2bfloat16(f);
    return *reinterpret_cast<short*>(&b);
}

// ================= PK fragment layout =================
// For row-major Mat[R][768] bf16: frag(rt,kc) occupies 1024B at
// (rt*NFK_+kc)*512 elems; lane slot = lane*8; content =
//   Mat[rt*16 + (lane&15)][kc*32 + (lane>>4)*8 + j],  j=0..7.
// This is EXACTLY the 16x16x32 MFMA A/B operand per lane, so a wave loads a
// fragment as ONE coalesced 1KB global_load_dwordx4. GEMMs need no LDS and
// no barriers: pure load->MFMA streams from L2 (r0-r5 showed the LDS pipe,
// ~240KB/CU-Ktile, was the 24%-MfmaUtil wall; this removes it entirely).

// ---------- cvt+pack: x->A-frags, W_attn/W_proj -> transposed B-frags ----------
#define XPK 3072                        // 12288 x-frags / 4 per block
#define WAPK 1728                       // (2304/32)*(768/32)
__global__ __launch_bounds__(256) void cvt_pk_kernel(
        const float* __restrict__ x,  bf16* __restrict__ xpk,
        const float* __restrict__ wa, bf16* __restrict__ wapk,
        const float* __restrict__ wp, bf16* __restrict__ wppk) {
    const int bid = blockIdx.x, t = threadIdx.x;
    if (bid < XPK) {
        const int lane = t & 63;
        const int gfrag = bid * 4 + (t >> 6);
        const int row = (gfrag / NFK_) * 16 + (lane & 15);
        const int col = (gfrag % NFK_) * 32 + (lane >> 4) * 8;
        const float4 v0 = *(const float4*)(x + (size_t)row * C_ + col);
        const float4 v1 = *(const float4*)(x + (size_t)row * C_ + col + 4);
        bfrag v;
        v[0] = bfbits(v0.x); v[1] = bfbits(v0.y); v[2] = bfbits(v0.z); v[3] = bfbits(v0.w);
        v[4] = bfbits(v1.x); v[5] = bfbits(v1.y); v[6] = bfbits(v1.z); v[7] = bfbits(v1.w);
        *(bfrag*)((unsigned short*)xpk + (size_t)gfrag * 512 + lane * 8) = v;
        return;
    }
    __shared__ float tile[32][33];      // tile[k_local][n_local]
    const float* w; bf16* wt; int N, tI;
    if (bid < XPK + WAPK) { w = wa; wt = wapk; N = N3_; tI = bid - XPK; }
    else                  { w = wp; wt = wppk; N = C_;  tI = bid - XPK - WAPK; }
    const int ntn = N / 32;
    const int n0 = (tI % ntn) * 32, k0 = (tI / ntn) * 32;
    const int tx = t & 31, ty = t >> 5;        // 32 x 8
    for (int i = ty; i < 32; i += 8) tile[i][tx] = w[(size_t)(k0 + i) * N + n0 + tx];
    __syncthreads();
    if (t < 128) {                      // 2 frags per 32x32 tile
        const int f = t >> 6, l = t & 63;
        const int nl = f * 16 + (l & 15), k8 = (l >> 4) * 8;
        bfrag v;
#pragma unroll
        for (int j = 0; j < 8; ++j) v[j] = bfbits(tile[k8 + j][nl]);
        const size_t fid = (size_t)(n0 / 16 + f) * NFK_ + (k0 / 32);
        *(bfrag*)((unsigned short*)wt + fid * 512 + (size_t)l * 8) = v;
    }
}

// ---------- barrier-free register-streaming GEMM core ----------
// 256 thr = 4 waves (2 row x 2 col), wave tile 64x96, acc[4][6] (96 AGPR).
// No LDS: each fragment is one coalesced 1KB dwordx4 from the PK layout.
// Compiler pipelines loads vs MFMA freely (no barriers); 3 blocks/CU TLP.
template<bool SWAPPED>
__device__ __forceinline__ void gemm_pk_core(
        const unsigned short* __restrict__ Ap0, const unsigned short* __restrict__ Bp0,
        const int rtA, const int rtB, const int lane, facc (&acc)[4][6]) {
    const unsigned short* Ap = Ap0 + (size_t)rtA * NFK_ * 512 + lane * 8;
    const unsigned short* Bp = Bp0 + (size_t)rtB * NFK_ * 512 + lane * 8;
#pragma unroll
    for (int i = 0; i < 4; ++i)
#pragma unroll
        for (int c = 0; c < 6; ++c)
#pragma unroll
            for (int r = 0; r < 4; ++r) acc[i][c][r] = 0.f;

    for (int kc = 0; kc < NFK_; kc += 2) {
        bfrag af[4][2];
#pragma unroll
        for (int i = 0; i < 4; ++i) {
            af[i][0] = *(const bfrag*)(Ap + (size_t)(i * NFK_ + kc) * 512);
            af[i][1] = *(const bfrag*)(Ap + (size_t)(i * NFK_ + kc + 1) * 512);
        }
#pragma unroll
        for (int c = 0; c < 6; ++c) {
            const bfrag b0 = *(const bfrag*)(Bp + (size_t)(c * NFK_ + kc) * 512);
            const bfrag b1 = *(const bfrag*)(Bp + (size_t)(c * NFK_ + kc + 1) * 512);
            // kk0 across i, then kk1: dependent-pair distance 4 (no b2b stall)
#pragma unroll
            for (int i = 0; i < 4; ++i) {
                if constexpr (SWAPPED)
                    acc[i][c] = __builtin_amdgcn_mfma_f32_16x16x32_bf16(b0, af[i][0], acc[i][c], 0, 0, 0);
                else
                    acc[i][c] = __builtin_amdgcn_mfma_f32_16x16x32_bf16(af[i][0], b0, acc[i][c], 0, 0, 0);
            }
#pragma unroll
            for (int i = 0; i < 4; ++i) {
                if constexpr (SWAPPED)
                    acc[i][c] = __builtin_amdgcn_mfma_f32_16x16x32_bf16(b1, af[i][1], acc[i][c], 0, 0, 0);
                else
                    acc[i][c] = __builtin_amdgcn_mfma_f32_16x16x32_bf16(af[i][1], b1, acc[i][c], 0, 0, 0);
            }
        }
    }
}

// qkv: A=xpk [8192x768] PK, B=wapk [2304x768] PK -> Q,K (swapped, packed 8B
// stores), Vt (non-swapped). Grid 768 = exactly 3 blocks/CU (launch_bounds 3).
// 2D XCD chunk map (r5): xcd owns 16 rows x 6 cols, col-major walk -> per-XCD
// working set (1 W col-panel + x panels) stays L2-resident.
__global__ __launch_bounds__(256, 3) void qkv_pk_kernel(
        const bf16* __restrict__ xpk, const bf16* __restrict__ wapk,
        const float* __restrict__ bias,
        bf16* __restrict__ Q, bf16* __restrict__ K, bf16* __restrict__ Vt) {
    const int id = blockIdx.x;
    const int xcd = id & 7, L = id >> 3;           // L in 0..95
    const int rgrp = xcd >> 1, cgrp = xcd & 1;     // 4 row-groups x 2 col-groups
    const int r_l = L & 15, c_l = L >> 4;          // 16 rows x 6 cols, col-major
    const int by = rgrp * 16 + r_l, bx = cgrp * 6 + c_l;
    const int m0 = by * 128, n0 = bx * 192;
    const int which = bx / 4;                      // block-uniform: 0=Q 1=K 2=V

    const int t = threadIdx.x, w = t >> 6, lane = t & 63;
    const int wr = (w >> 1) * 64, wc = (w & 1) * 96;
    const int rtA = (m0 + wr) >> 4, rtB = (n0 + wc) >> 4;

    facc acc[4][6];
    if (which < 2) gemm_pk_core<true >((const unsigned short*)xpk, (const unsigned short*)wapk, rtA, rtB, lane, acc);
    else           gemm_pk_core<false>((const unsigned short*)xpk, (const unsigned short*)wapk, rtA, rtB, lane, acc);

    const int fr = lane & 15, quad = lane >> 4;
    const int bb = m0 >> 10;                       // uniform batch index
    if (which < 2) {
        bf16* dst = which ? K : Q;
        const float sc = which ? 1.0f : QSCALE_;
#pragma unroll
        for (int i = 0; i < 4; ++i) {
            const int tt = (m0 & 1023) + wr + i * 16 + fr;     // token (lane-major)
#pragma unroll
            for (int c = 0; c < 6; ++c) {
                const int colbase = n0 + wc + c * 16 + quad * 4;
                const int cc = colbase - which * C_;
                const int h = cc >> 6, d0 = cc & 63;
                const float4 bv = *(const float4*)(bias + colbase);
                short4v pk;
                pk[0] = bfbits((acc[i][c][0] + bv.x) * sc);
                pk[1] = bfbits((acc[i][c][1] + bv.y) * sc);
                pk[2] = bfbits((acc[i][c][2] + bv.z) * sc);
                pk[3] = bfbits((acc[i][c][3] + bv.w) * sc);
                *(short4v*)(dst + ((size_t)(bb * H_ + h) * T_ + tt) * HD_ + d0) = pk;
            }
        }
    } else {
#pragma unroll
        for (int i = 0; i < 4; ++i) {
            const int tt0 = (m0 & 1023) + wr + i * 16 + quad * 4;  // token, +r over pack
#pragma unroll
            for (int c = 0; c < 6; ++c) {
                const int col = n0 + wc + c * 16 + fr;
                const int cc = col - 2 * C_;
                const int h = cc >> 6, d = cc & 63;
                const float bv = bias[col];
                short4v pk;
                pk[0] = bfbits(acc[i][c][0] + bv);
                pk[1] = bfbits(acc[i][c][1] + bv);
                pk[2] = bfbits(acc[i][c][2] + bv);
                pk[3] = bfbits(acc[i][c][3] + bv);
                *(short4v*)(Vt + ((size_t)(bb * H_ + h) * HD_ + d) * T_ + tt0) = pk;
            }
        }
    }
}

// proj: A = Y-PK (written packed by flash), B = wppk -> fp32 out + bias
// (swapped). Grid 256 = exactly 1 block/CU, single clean round.
__global__ __launch_bounds__(256, 3) void proj_pk_kernel(
        const bf16* __restrict__ ypk, const bf16* __restrict__ wppk,
        const float* __restrict__ bias, float* __restrict__ out) {
    const int id = blockIdx.x;
    const int wg = (id & 7) * 32 + (id >> 3);      // bijective XCD swizzle (256%8==0)
    const int bx = wg & 3, by = wg >> 2;
    const int m0 = by * 128, n0 = bx * 192;

    const int t = threadIdx.x, w = t >> 6, lane = t & 63;
    const int wr = (w >> 1) * 64, wc = (w & 1) * 96;
    const int rtA = (m0 + wr) >> 4, rtB = (n0 + wc) >> 4;

    facc acc[4][6];
    gemm_pk_core<true>((const unsigned short*)ypk, (const unsigned short*)wppk, rtA, rtB, lane, acc);

    const int fr = lane & 15, quad = lane >> 4;
#pragma unroll
    for (int i = 0; i < 4; ++i) {
        const int row = m0 + wr + i * 16 + fr;
#pragma unroll
        for (int c = 0; c < 6; ++c) {
            const int colbase = n0 + wc + c * 16 + quad * 4;
            const float4 bv = *(const float4*)(bias + colbase);
            float4 v;
            v.x = acc[i][c][0] + bv.x;
            v.y = acc[i][c][1] + bv.y;
            v.z = acc[i][c][2] + bv.z;
            v.w = acc[i][c][3] + bv.w;
            *(float4*)(out + (size_t)row * C_ + colbase) = v;
        }
    }
}

// ---------- flash attention: exp2 static-max softmax + 2 K-tiles per barrier;
// epilogue now emits Y in PK-fragment layout (2 coalesced 16B stores/thread
// via a per-wave sP bounce) so proj can stream it LDS-free. ----------
__global__ __launch_bounds__(256) void flash_attn_kernel(
        const bf16* __restrict__ Q, const bf16* __restrict__ K,
        const bf16* __restrict__ Vt, bf16* __restrict__ Y) {
    const int id   = blockIdx.x;
    const int bh   = (id & 7) * 12 + ((id >> 3) % 12);    // XCD affinity
    const int qpair = (id >> 3) / 12;                     // 0..7
    const int t = threadIdx.x, w = t >> 6, lane = t & 63;
    const int fr = lane & 15, quad = lane >> 4, fq = quad * 8;

    __shared__ bf16 sK[2][64 * 64];       // [buf][key][dim], chunk-swizzled
    __shared__ bf16 sVt[2][64 * 64];      // [buf][dim][key], chunk-swizzled
    __shared__ bf16 sP[4][16][72];        // wave-private P / O-bounce, stride 72

    const bf16* Kbh = K  + (size_t)bh * T_ * HD_;
    const bf16* Vbh = Vt + (size_t)bh * HD_ * T_;
    const int b_ = bh / H_, h_ = bh % H_;

    const int srow = t >> 3;                                // 0..31 (staging row)
    const int sgc  = ((t & 7) ^ (srow & 7)) * 8;            // swizzled source chunk
    const int c0   = (quad ^ (fr & 7)) * 8;                 // swizzled read chunk

    for (int phase = 0; phase < 2; ++phase) {
        const int qt = (phase == 0) ? (15 - qpair) : qpair; // heavy tile first
        const int q0 = qt * 64;

        const bf16* qbase = Q + ((size_t)bh * T_ + q0 + w * 16 + fr) * HD_;
        bfrag qa0 = *(const bfrag*)(qbase + fq);
        bfrag qa1 = *(const bfrag*)(qbase + 32 + fq);

        facc o[4];
        for (int nb = 0; nb < 4; ++nb) for (int r = 0; r < 4; ++r) o[nb][r] = 0.f;
        float rowl[4] = {0.f, 0.f, 0.f, 0.f};

        auto tile_step = [&](int kt, const bf16* sKp, const bf16* sVp) {
            const int k0 = kt * 64;
            facc s[4];
            for (int nb = 0; nb < 4; ++nb) for (int r = 0; r < 4; ++r) s[nb][r] = 0.f;
            __builtin_amdgcn_s_setprio(1);                     // T5: favor MFMA wave
            for (int nb = 0; nb < 4; ++nb) {
                const bf16* kr = sKp + (nb * 16 + fr) * 64;
                bfrag kb0 = *(const bfrag*)(kr + c0);
                bfrag kb1 = *(const bfrag*)(kr + (c0 ^ 32));
                s[nb] = __builtin_amdgcn_mfma_f32_16x16x32_bf16(qa0, kb0, s[nb], 0, 0, 0);
                s[nb] = __builtin_amdgcn_mfma_f32_16x16x32_bf16(qa1, kb1, s[nb], 0, 0, 0);
            }
            __builtin_amdgcn_s_setprio(0);
            const int mrow0 = q0 + w * 16 + quad * 4;   // + r
            float p[4][4];
            if (kt == qt) {
                for (int nb = 0; nb < 4; ++nb) {
                    const int n_g = k0 + nb * 16 + fr;
                    for (int r = 0; r < 4; ++r) {
                        const float a = (n_g > mrow0 + r) ? -1e30f : s[nb][r] - M2_;
                        p[nb][r] = fexp2(a);
                    }
                }
            } else {
                for (int nb = 0; nb < 4; ++nb)
                    for (int r = 0; r < 4; ++r)
                        p[nb][r] = fexp2(s[nb][r] - M2_);
            }
            for (int r = 0; r < 4; ++r)
                rowl[r] += p[0][r] + p[1][r] + p[2][r] + p[3][r];
            for (int nb = 0; nb < 4; ++nb)
                for (int r = 0; r < 4; ++r)
                    sP[w][quad * 4 + r][nb * 16 + fr] = __float2bfloat16(p[nb][r]);
            bfrag pa0 = *(const bfrag*)(&sP[w][fr][fq]);
            bfrag pa1 = *(const bfrag*)(&sP[w][fr][32 + fq]);
            __builtin_amdgcn_s_setprio(1);                     // T5: favor MFMA wave
            for (int nb = 0; nb < 4; ++nb) {
                const bf16* vr = sVp + (nb * 16 + fr) * 64;
                bfrag vb0 = *(const bfrag*)(vr + c0);
                bfrag vb1 = *(const bfrag*)(vr + (c0 ^ 32));
                o[nb] = __builtin_amdgcn_mfma_f32_16x16x32_bf16(pa0, vb0, o[nb], 0, 0, 0);
                o[nb] = __builtin_amdgcn_mfma_f32_16x16x32_bf16(pa1, vb1, o[nb], 0, 0, 0);
            }
            __builtin_amdgcn_s_setprio(0);
        };

        for (int kt = 0; kt <= qt; kt += 2) {
            const int k0 = kt * 64;
            const bool two = (kt + 1 <= qt);
            gload_lds16(Kbh + (size_t)(k0 + srow) * HD_ + sgc,      sK[0] + t * 8);
            gload_lds16(Kbh + (size_t)(k0 + 32 + srow) * HD_ + sgc, sK[0] + 2048 + t * 8);
            gload_lds16(Vbh + (size_t)srow * T_ + k0 + sgc,         sVt[0] + t * 8);
            gload_lds16(Vbh + (size_t)(srow + 32) * T_ + k0 + sgc,  sVt[0] + 2048 + t * 8);
            if (two) {
                const int k1 = k0 + 64;
                gload_lds16(Kbh + (size_t)(k1 + srow) * HD_ + sgc,      sK[1] + t * 8);
                gload_lds16(Kbh + (size_t)(k1 + 32 + srow) * HD_ + sgc, sK[1] + 2048 + t * 8);
                gload_lds16(Vbh + (size_t)srow * T_ + k1 + sgc,         sVt[1] + t * 8);
                gload_lds16(Vbh + (size_t)(srow + 32) * T_ + k1 + sgc,  sVt[1] + 2048 + t * 8);
            }
            __syncthreads();
            tile_step(kt, sK[0], sVt[0]);
            if (two) tile_step(kt + 1, sK[1], sVt[1]);
            __syncthreads();
        }

        // epilogue: normalize, bounce O through sP[w], emit Y in PK layout
        float invr[4];
        for (int r = 0; r < 4; ++r) {
            float l = rowl[r];
            l += __shfl_xor(l, 1);
            l += __shfl_xor(l, 2);
            l += __shfl_xor(l, 4);
            l += __shfl_xor(l, 8);
            invr[r] = 1.0f / l;
        }
        for (int nb = 0; nb < 4; ++nb)
            for (int r = 0; r < 4; ++r)
                sP[w][quad * 4 + r][nb * 16 + fr] = __float2bfloat16(o[nb][r] * invr[r]);
        const int mt = (b_ * T_ + q0 + w * 16) >> 4;       // global token frag-tile
        unsigned short* Yp = (unsigned short*)Y;
#pragma unroll
        for (int kk2 = 0; kk2 < 2; ++kk2) {
            const int kc = h_ * 2 + kk2;                   // k-chunk of this head
            bfrag v = *(const bfrag*)(&sP[w][lane & 15][kk2 * 32 + (lane >> 4) * 8]);
            *(bfrag*)(Yp + (size_t)(mt * NFK_ + kc) * 512 + (size_t)lane * 8) = v;
        }
    }
}

extern "C" void kernel_launch(void* const* d_in, const int* in_sizes, int n_in,
                              void* d_out, int out_size, void* d_ws, size_t ws_size,
                              hipStream_t stream) {
    const float* x      = (const float*)d_in[0];
    const float* W_attn = (const float*)d_in[1];
    const float* b_attn = (const float*)d_in[2];
    const float* W_proj = (const float*)d_in[3];
    const float* b_proj = (const float*)d_in[4];
    float* out = (float*)d_out;

    const size_t per = (size_t)B_ * H_ * T_ * HD_;   // 6291456 bf16
    bf16* Q   = (bf16*)d_ws;
    bf16* K   = Q + per;
    bf16* Vt  = K + per;                 // transposed V [B,H,64,T]
    bf16* XbY = Vt + per;                // x PK-frags, later Y PK-frags
    bf16* WaT = XbY + per;               // W_attn^T PK-frags
    bf16* WpT = WaT + (size_t)N3_ * C_;  // W_proj^T PK-frags

    cvt_pk_kernel<<<dim3(XPK + WAPK + 576), dim3(256), 0, stream>>>(
        x, XbY, W_attn, WaT, W_proj, WpT);
    qkv_pk_kernel<<<dim3(768), dim3(256), 0, stream>>>(
        XbY, WaT, b_attn, Q, K, Vt);
    flash_attn_kernel<<<dim3(768), dim3(256), 0, stream>>>(Q, K, Vt, XbY);
    proj_pk_kernel<<<dim3(256), dim3(256), 0, stream>>>(
        XbY, WpT, b_proj, out);
}

// Round 7
// 190.078 us; speedup vs baseline: 1.1410x; 1.1410x over previous
//
#include <hip/hip_runtime.h>
#include <hip/hip_bf16.h>

typedef __hip_bfloat16 bf16;
typedef __attribute__((ext_vector_type(8))) short  bfrag;   // 8 bf16 (4 VGPR) MFMA A/B frag
typedef __attribute__((ext_vector_type(4))) float  facc;    // MFMA C/D frag
typedef __attribute__((ext_vector_type(4))) short  short4v; // 4 bf16 = 8B packed store

#define B_   8
#define T_   1024
#define C_   768
#define H_   12
#define HD_  64
#define M_   (B_ * T_)   // 8192
#define N3_  (3 * C_)    // 2304

// Q is stored pre-scaled by 0.125*log2(e) so flash softmax is p = exp2(s - M2)
#define QSCALE_ 0.18033688011112042f
#define M2_     17.312340490667562f

__device__ __forceinline__ float fexp2(float x) { return __builtin_amdgcn_exp2f(x); }

__device__ __forceinline__ void gload_lds16(const bf16* g, bf16* l) {
    __builtin_amdgcn_global_load_lds((const __attribute__((address_space(1))) void*)g,
                                     (__attribute__((address_space(3))) void*)l, 16, 0, 0);
}
__device__ __forceinline__ short bfbits(float f) {
    bf16 b = __float2bfloat16(f);
    return *reinterpret_cast<short*>(&b);
}

#define WAIT_VM(N) asm volatile("s_waitcnt vmcnt(" #N ")" ::: "memory")

// ---------- fused converts: x->bf16, W_attn->bf16^T, W_proj->bf16^T ----------
#define XBLK 6144                       // x: 6291456 / (256*4)
#define WABLK 1728                      // (2304/32)*(768/32)
__global__ __launch_bounds__(256) void cvt_all_kernel(
        const float* __restrict__ x,  bf16* __restrict__ xb,
        const float* __restrict__ wa, bf16* __restrict__ wat,
        const float* __restrict__ wp, bf16* __restrict__ wpt) {
    const int bid = blockIdx.x, t = threadIdx.x;
    if (bid < XBLK) {
        const size_t i = ((size_t)bid * 256 + t) * 4;
        const float4 v = *(const float4*)(x + i);
        bf16* o = xb + i;
        o[0] = __float2bfloat16(v.x); o[1] = __float2bfloat16(v.y);
        o[2] = __float2bfloat16(v.z); o[3] = __float2bfloat16(v.w);
        return;
    }
    __shared__ float tile[32][33];
    const float* w; bf16* wt; int N, tI;
    if (bid < XBLK + WABLK) { w = wa; wt = wat; N = N3_; tI = bid - XBLK; }
    else                    { w = wp; wt = wpt; N = C_;  tI = bid - XBLK - WABLK; }
    const int ntn = N / 32;
    const int n0 = (tI % ntn) * 32, k0 = (tI / ntn) * 32;
    const int tx = t & 31, ty = t >> 5;        // 32 x 8
    for (int i = ty; i < 32; i += 8) tile[i][tx] = w[(size_t)(k0 + i) * N + n0 + tx];
    __syncthreads();
    for (int i = ty; i < 32; i += 8)
        wt[(size_t)(n0 + i) * C_ + k0 + tx] = __float2bfloat16(tile[tx][i]);
}

// ---------- 256x256 8-wave counted-vmcnt GEMM (m201-anchored, race-free) ----------
// 512 thr = 8 waves (2 row x 4 col), wave tile 128x64, acc[8][4] (128 regs).
// LDS 128KB: A dbuf 2x[256x64], B dbuf 2x[256x64], XOR chunk-swizzled.
// Per K-tile: WAIT_VM(8) + barrier (tile's 8 stage-loads/thread complete; the
// NEXT tile's 8 stay in flight) -> B-frags read ONCE (held live), A per
// row-half -> 64 MFMA -> barrier -> refill this buffer (tile t+2).
// Stage lands >= 1 full tile-time before its first read. vmcnt never 0 until
// the last tile. Minimal LDS traffic: 24KB/wave/tile -> ~62% MfmaUtil ceiling.

template<bool SWAPPED>
__device__ __forceinline__ void gemm256_core(
        const bf16* __restrict__ Ap, const bf16* __restrict__ Bp,
        const int m0, const int n0, bf16* smem, facc (&acc)[8][4]) {
    constexpr int KD = 768;
    bf16* As = smem;                      // [2][256*64]
    bf16* Bs = smem + 2 * 16384;          // [2][256*64]
    const int t = threadIdx.x, w = t >> 6, lane = t & 63;
    const int wm = (w >> 2) * 128;                   // 2 row-waves
    const int wn = (w & 3) * 64;                     // 4 col-waves
    const int fr = lane & 15, quad = lane >> 4;
    const int pc0 = (quad ^ (fr & 7)) * 8;           // swizzled read chunk, kk=0
    const int pc1 = ((quad + 4) ^ (fr & 7)) * 8;     // kk=1
    const int srow = t >> 3;                         // 0..63 staging row
    const int schunk = ((t & 7) ^ (srow & 7)) * 8;   // swizzled source chunk
    const int sdo = t * 8;                           // linear LDS dest

    const bf16* Ag = Ap + (size_t)(m0 + srow) * KD + schunk;
    const bf16* Bg = Bp + (size_t)(n0 + srow) * KD + schunk;

#pragma unroll
    for (int i = 0; i < 8; ++i)
#pragma unroll
        for (int j = 0; j < 4; ++j)
#pragma unroll
            for (int r = 0; r < 4; ++r) acc[i][j][r] = 0.f;

    auto stage = [&](bf16* Ab, bf16* Bb, int k0) {   // 8 gloads/thread: A 4 + B 4
#pragma unroll
        for (int r = 0; r < 4; ++r) {
            gload_lds16(Ag + (size_t)(r * 64) * KD + k0, Ab + r * 4096 + sdo);
            gload_lds16(Bg + (size_t)(r * 64) * KD + k0, Bb + r * 4096 + sdo);
        }
    };

    auto tilecomp = [&](const bf16* AsC, const bf16* BsC) {
        bfrag bf[4][2];
#pragma unroll
        for (int j = 0; j < 4; ++j) {                // B read once, held live
            const bf16* br = BsC + (wn + j * 16 + fr) * 64;
            bf[j][0] = *(const bfrag*)(br + pc0);
            bf[j][1] = *(const bfrag*)(br + pc1);
        }
#pragma unroll
        for (int h = 0; h < 2; ++h) {                // row halves: A read once
            bfrag af[4][2];
#pragma unroll
            for (int i = 0; i < 4; ++i) {
                const bf16* ar = AsC + (wm + h * 64 + i * 16 + fr) * 64;
                af[i][0] = *(const bfrag*)(ar + pc0);
                af[i][1] = *(const bfrag*)(ar + pc1);
            }
            __builtin_amdgcn_s_setprio(1);
#pragma unroll
            for (int j = 0; j < 4; ++j)              // all kk0 (16 indep)
#pragma unroll
                for (int i = 0; i < 4; ++i) {
                    facc& a = acc[h * 4 + i][j];
                    if constexpr (SWAPPED)
                        a = __builtin_amdgcn_mfma_f32_16x16x32_bf16(bf[j][0], af[i][0], a, 0, 0, 0);
                    else
                        a = __builtin_amdgcn_mfma_f32_16x16x32_bf16(af[i][0], bf[j][0], a, 0, 0, 0);
                }
#pragma unroll
            for (int j = 0; j < 4; ++j)              // all kk1 (dep distance 16)
#pragma unroll
                for (int i = 0; i < 4; ++i) {
                    facc& a = acc[h * 4 + i][j];
                    if constexpr (SWAPPED)
                        a = __builtin_amdgcn_mfma_f32_16x16x32_bf16(bf[j][1], af[i][1], a, 0, 0, 0);
                    else
                        a = __builtin_amdgcn_mfma_f32_16x16x32_bf16(af[i][1], bf[j][1], a, 0, 0, 0);
                }
            __builtin_amdgcn_s_setprio(0);
        }
    };

    // prologue: tiles 0 (buf0) and 1 (buf1): 16 loads/thread in flight
    stage(As, Bs, 0);
    stage(As + 16384, Bs + 16384, 64);

    for (int it = 0; it < 6; ++it) {
        // ---- tile a = 2it (buf0) ----
        WAIT_VM(8);                          // a complete; b's 8 stay in flight
        __builtin_amdgcn_s_barrier();
        __builtin_amdgcn_sched_barrier(0);
        tilecomp(As, Bs);
        __builtin_amdgcn_sched_barrier(0);
        __builtin_amdgcn_s_barrier();        // all reads of buf0 done
        if (it < 5) stage(As, Bs, (2 * it + 2) * 64);
        // ---- tile b = 2it+1 (buf1) ----
        if (it < 5) { WAIT_VM(8); } else { WAIT_VM(0); }
        __builtin_amdgcn_s_barrier();
        __builtin_amdgcn_sched_barrier(0);
        tilecomp(As + 16384, Bs + 16384);
        __builtin_amdgcn_sched_barrier(0);
        __builtin_amdgcn_s_barrier();        // all reads of buf1 done
        if (it < 5) stage(As + 16384, Bs + 16384, (2 * it + 3) * 64);
    }
}

// qkv: A=xb [8192x768], Bt=WaT [2304x768] -> Q,K (swapped, packed 8B stores),
// Vt [B,H,64,T] (non-swapped). Grid 288 = 32 by x 9 bx; 256-col blocks split
// Q/K/V cleanly (bx/3). Per-XCD chunk: 4 consecutive by x all 9 bx col-major.
__global__ __launch_bounds__(512, 2) void qkv8p_kernel(
        const bf16* __restrict__ xb, const bf16* __restrict__ wat,
        const float* __restrict__ bias,
        bf16* __restrict__ Q, bf16* __restrict__ K, bf16* __restrict__ Vt) {
    extern __shared__ bf16 smem[];
    const int id = blockIdx.x;
    const int xcd = id & 7, L = id >> 3;           // L in 0..35
    const int by = xcd * 4 + (L & 3), bx = L >> 2; // col-major walk per XCD
    const int m0 = by * 256, n0 = bx * 256;
    const int which = bx / 3;                      // block-uniform: 0=Q 1=K 2=V

    facc acc[8][4];
    if (which < 2) gemm256_core<true >(xb, wat, m0, n0, smem, acc);
    else           gemm256_core<false>(xb, wat, m0, n0, smem, acc);

    const int t = threadIdx.x, w = t >> 6, lane = t & 63;
    const int wm = (w >> 2) * 128, wn = (w & 3) * 64;
    const int fr = lane & 15, quad = lane >> 4;
    const int bb = m0 >> 10;                       // uniform batch (256 | 1024)
    if (which < 2) {
        bf16* dst = which ? K : Q;
        const float sc = which ? 1.0f : QSCALE_;
#pragma unroll
        for (int i = 0; i < 8; ++i) {
            const int tt = (m0 & 1023) + wm + i * 16 + fr;     // token (lane-major)
#pragma unroll
            for (int j = 0; j < 4; ++j) {
                const int colbase = n0 + wn + j * 16 + quad * 4;
                const int cc = colbase - which * C_;
                const int h = cc >> 6, d0 = cc & 63;
                const float4 bv = *(const float4*)(bias + colbase);
                short4v pk;
                pk[0] = bfbits((acc[i][j][0] + bv.x) * sc);
                pk[1] = bfbits((acc[i][j][1] + bv.y) * sc);
                pk[2] = bfbits((acc[i][j][2] + bv.z) * sc);
                pk[3] = bfbits((acc[i][j][3] + bv.w) * sc);
                *(short4v*)(dst + ((size_t)(bb * H_ + h) * T_ + tt) * HD_ + d0) = pk;
            }
        }
    } else {
#pragma unroll
        for (int i = 0; i < 8; ++i) {
            const int tt0 = (m0 & 1023) + wm + i * 16 + quad * 4;  // token, +r over pack
#pragma unroll
            for (int j = 0; j < 4; ++j) {
                const int col = n0 + wn + j * 16 + fr;
                const int cc = col - 2 * C_;
                const int h = cc >> 6, d = cc & 63;
                const float bv = bias[col];
                short4v pk;
                pk[0] = bfbits(acc[i][j][0] + bv);
                pk[1] = bfbits(acc[i][j][1] + bv);
                pk[2] = bfbits(acc[i][j][2] + bv);
                pk[3] = bfbits(acc[i][j][3] + bv);
                *(short4v*)(Vt + ((size_t)(bb * H_ + h) * HD_ + d) * T_ + tt0) = pk;
            }
        }
    }
}

// ---------- proj: r5 counted-vmcnt BN=96 core (known-good), grid 512 ----------
template<bool SWAPPED>
__device__ __forceinline__ void gemm_cv_core(
        const bf16* __restrict__ Ap, const bf16* __restrict__ Bp,
        const int m0, const int n0, const int kt0,
        bf16* smem, facc (&acc)[4][3]) {
    constexpr int KD = 768, NT = 12;
    bf16* As = smem;                      // [2][128*64]
    bf16* Bs = smem + 2 * 8192;           // [2][96*64]
    const int t = threadIdx.x, w = t >> 6, lane = t & 63;
    const int wrow = (w >> 1) * 64;
    const int wcol = (w & 1) * 48;
    const int fr = lane & 15, quad = lane >> 4;
    const int pc0 = (quad ^ (fr & 7)) * 8;
    const int pc1 = ((quad + 4) ^ (fr & 7)) * 8;
    const int srow = t >> 3;
    const int schunk = ((t & 7) ^ (srow & 7)) * 8;
    const int sdo = t * 8;

    const bf16* Ag = Ap + (size_t)(m0 + srow) * KD + schunk;
    const bf16* Bg = Bp + (size_t)(n0 + srow) * KD + schunk;

#pragma unroll
    for (int i = 0; i < 4; ++i)
#pragma unroll
        for (int c = 0; c < 3; ++c)
#pragma unroll
            for (int r = 0; r < 4; ++r) acc[i][c][r] = 0.f;

    auto stageA = [&](bf16* dst, int k0) {
        const bf16* s = Ag + k0;
        bf16* d = dst + sdo;
#pragma unroll
        for (int r = 0; r < 4; ++r)
            gload_lds16(s + (size_t)(r * 32) * KD, d + r * 2048);
    };
    auto stageB = [&](bf16* dst, int k0) {
        const bf16* s = Bg + k0;
        bf16* d = dst + sdo;
#pragma unroll
        for (int r = 0; r < 3; ++r)
            gload_lds16(s + (size_t)(r * 32) * KD, d + r * 2048);
    };

    stageA(As, kt0 * 64);
    stageB(Bs, kt0 * 64);

    int kt = kt0;
#pragma unroll 2
    for (int s = 0; s < NT; ++s) {
        const int cb = s & 1;
        const bf16* AsC = As + cb * 8192;
        const bf16* BsC = Bs + cb * 6144;
        const int ktn = (kt + 1 == NT) ? 0 : kt + 1;
        if (s + 1 < NT) {
            stageA(As + (cb ^ 1) * 8192, ktn * 64);
            stageB(Bs + (cb ^ 1) * 6144, ktn * 64);
            WAIT_VM(7);
        } else {
            WAIT_VM(0);
        }
        __builtin_amdgcn_s_barrier();
        __builtin_amdgcn_sched_barrier(0);
        __builtin_amdgcn_s_setprio(1);
        bfrag af[4][2];
#pragma unroll
        for (int i = 0; i < 4; ++i) {
            const bf16* ar = AsC + (wrow + i * 16 + fr) * 64;
            af[i][0] = *(const bfrag*)(ar + pc0);
            af[i][1] = *(const bfrag*)(ar + pc1);
        }
#pragma unroll
        for (int c = 0; c < 3; ++c) {
            const bf16* br = BsC + (wcol + c * 16 + fr) * 64;
            bfrag b0 = *(const bfrag*)(br + pc0);
            bfrag b1 = *(const bfrag*)(br + pc1);
#pragma unroll
            for (int i = 0; i < 4; ++i) {
                if constexpr (SWAPPED) {
                    acc[i][c] = __builtin_amdgcn_mfma_f32_16x16x32_bf16(b0, af[i][0], acc[i][c], 0, 0, 0);
                    acc[i][c] = __builtin_amdgcn_mfma_f32_16x16x32_bf16(b1, af[i][1], acc[i][c], 0, 0, 0);
                } else {
                    acc[i][c] = __builtin_amdgcn_mfma_f32_16x16x32_bf16(af[i][0], b0, acc[i][c], 0, 0, 0);
                    acc[i][c] = __builtin_amdgcn_mfma_f32_16x16x32_bf16(af[i][1], b1, acc[i][c], 0, 0, 0);
                }
            }
        }
        __builtin_amdgcn_s_setprio(0);
        __builtin_amdgcn_sched_barrier(0);
        __builtin_amdgcn_s_barrier();
        kt = ktn;
    }
}

__global__ __launch_bounds__(256, 2) void proj_p_kernel(
        const bf16* __restrict__ y, const bf16* __restrict__ wpt,
        const float* __restrict__ bias, float* __restrict__ out) {
    extern __shared__ bf16 smem[];
    const int id = blockIdx.x;
    const int xcd = id & 7, L = id >> 3;           // L in 0..63
    const int rgrp = xcd >> 1, cgrp = xcd & 1;
    const int r_l = L & 15, c_l = L >> 4;
    const int by = rgrp * 16 + r_l, bx = cgrp * 4 + c_l;
    const int m0 = by * 128, n0 = bx * 96;
    const int kt0 = L % 12;

    facc acc[4][3];
    gemm_cv_core<true>(y, wpt, m0, n0, kt0, smem, acc);

    const int t = threadIdx.x, w = t >> 6, lane = t & 63;
    const int wr = (w >> 1) * 64, wc = (w & 1) * 48;
    const int fr = lane & 15, quad = lane >> 4;
#pragma unroll
    for (int i = 0; i < 4; ++i) {
        const int row = m0 + wr + i * 16 + fr;
#pragma unroll
        for (int c = 0; c < 3; ++c) {
            const int colbase = n0 + wc + c * 16 + quad * 4;
            const float4 bv = *(const float4*)(bias + colbase);
            float4 v;
            v.x = acc[i][c][0] + bv.x;
            v.y = acc[i][c][1] + bv.y;
            v.z = acc[i][c][2] + bv.z;
            v.w = acc[i][c][3] + bv.w;
            *(float4*)(out + (size_t)row * C_ + colbase) = v;
        }
    }
}

// ---------- flash attention: exp2 static-max softmax + 2 K-tiles per barrier ----------
__global__ __launch_bounds__(256) void flash_attn_kernel(
        const bf16* __restrict__ Q, const bf16* __restrict__ K,
        const bf16* __restrict__ Vt, bf16* __restrict__ Y) {
    const int id   = blockIdx.x;
    const int bh   = (id & 7) * 12 + ((id >> 3) % 12);    // XCD affinity
    const int qpair = (id >> 3) / 12;                     // 0..7
    const int t = threadIdx.x, w = t >> 6, lane = t & 63;
    const int fr = lane & 15, quad = lane >> 4, fq = quad * 8;

    __shared__ bf16 sK[2][64 * 64];
    __shared__ bf16 sVt[2][64 * 64];
    __shared__ bf16 sP[4][16][72];

    const bf16* Kbh = K  + (size_t)bh * T_ * HD_;
    const bf16* Vbh = Vt + (size_t)bh * HD_ * T_;
    const int b_ = bh / H_, h_ = bh % H_;

    const int srow = t >> 3;
    const int sgc  = ((t & 7) ^ (srow & 7)) * 8;
    const int c0   = (quad ^ (fr & 7)) * 8;

    for (int phase = 0; phase < 2; ++phase) {
        const int qt = (phase == 0) ? (15 - qpair) : qpair;
        const int q0 = qt * 64;

        const bf16* qbase = Q + ((size_t)bh * T_ + q0 + w * 16 + fr) * HD_;
        bfrag qa0 = *(const bfrag*)(qbase + fq);
        bfrag qa1 = *(const bfrag*)(qbase + 32 + fq);

        facc o[4];
        for (int nb = 0; nb < 4; ++nb) for (int r = 0; r < 4; ++r) o[nb][r] = 0.f;
        float rowl[4] = {0.f, 0.f, 0.f, 0.f};

        auto tile_step = [&](int kt, const bf16* sKp, const bf16* sVp) {
            const int k0 = kt * 64;
            facc s[4];
            for (int nb = 0; nb < 4; ++nb) for (int r = 0; r < 4; ++r) s[nb][r] = 0.f;
            __builtin_amdgcn_s_setprio(1);
            for (int nb = 0; nb < 4; ++nb) {
                const bf16* kr = sKp + (nb * 16 + fr) * 64;
                bfrag kb0 = *(const bfrag*)(kr + c0);
                bfrag kb1 = *(const bfrag*)(kr + (c0 ^ 32));
                s[nb] = __builtin_amdgcn_mfma_f32_16x16x32_bf16(qa0, kb0, s[nb], 0, 0, 0);
                s[nb] = __builtin_amdgcn_mfma_f32_16x16x32_bf16(qa1, kb1, s[nb], 0, 0, 0);
            }
            __builtin_amdgcn_s_setprio(0);
            const int mrow0 = q0 + w * 16 + quad * 4;
            float p[4][4];
            if (kt == qt) {
                for (int nb = 0; nb < 4; ++nb) {
                    const int n_g = k0 + nb * 16 + fr;
                    for (int r = 0; r < 4; ++r) {
                        const float a = (n_g > mrow0 + r) ? -1e30f : s[nb][r] - M2_;
                        p[nb][r] = fexp2(a);
                    }
                }
            } else {
                for (int nb = 0; nb < 4; ++nb)
                    for (int r = 0; r < 4; ++r)
                        p[nb][r] = fexp2(s[nb][r] - M2_);
            }
            for (int r = 0; r < 4; ++r)
                rowl[r] += p[0][r] + p[1][r] + p[2][r] + p[3][r];
            for (int nb = 0; nb < 4; ++nb)
                for (int r = 0; r < 4; ++r)
                    sP[w][quad * 4 + r][nb * 16 + fr] = __float2bfloat16(p[nb][r]);
            bfrag pa0 = *(const bfrag*)(&sP[w][fr][fq]);
            bfrag pa1 = *(const bfrag*)(&sP[w][fr][32 + fq]);
            __builtin_amdgcn_s_setprio(1);
            for (int nb = 0; nb < 4; ++nb) {
                const bf16* vr = sVp + (nb * 16 + fr) * 64;
                bfrag vb0 = *(const bfrag*)(vr + c0);
                bfrag vb1 = *(const bfrag*)(vr + (c0 ^ 32));
                o[nb] = __builtin_amdgcn_mfma_f32_16x16x32_bf16(pa0, vb0, o[nb], 0, 0, 0);
                o[nb] = __builtin_amdgcn_mfma_f32_16x16x32_bf16(pa1, vb1, o[nb], 0, 0, 0);
            }
            __builtin_amdgcn_s_setprio(0);
        };

        for (int kt = 0; kt <= qt; kt += 2) {
            const int k0 = kt * 64;
            const bool two = (kt + 1 <= qt);
            gload_lds16(Kbh + (size_t)(k0 + srow) * HD_ + sgc,      sK[0] + t * 8);
            gload_lds16(Kbh + (size_t)(k0 + 32 + srow) * HD_ + sgc, sK[0] + 2048 + t * 8);
            gload_lds16(Vbh + (size_t)srow * T_ + k0 + sgc,         sVt[0] + t * 8);
            gload_lds16(Vbh + (size_t)(srow + 32) * T_ + k0 + sgc,  sVt[0] + 2048 + t * 8);
            if (two) {
                const int k1 = k0 + 64;
                gload_lds16(Kbh + (size_t)(k1 + srow) * HD_ + sgc,      sK[1] + t * 8);
                gload_lds16(Kbh + (size_t)(k1 + 32 + srow) * HD_ + sgc, sK[1] + 2048 + t * 8);
                gload_lds16(Vbh + (size_t)srow * T_ + k1 + sgc,         sVt[1] + t * 8);
                gload_lds16(Vbh + (size_t)(srow + 32) * T_ + k1 + sgc,  sVt[1] + 2048 + t * 8);
            }
            __syncthreads();
            tile_step(kt, sK[0], sVt[0]);
            if (two) tile_step(kt + 1, sK[1], sVt[1]);
            __syncthreads();
        }

        for (int r = 0; r < 4; ++r) {
            float l = rowl[r];
            l += __shfl_xor(l, 1);
            l += __shfl_xor(l, 2);
            l += __shfl_xor(l, 4);
            l += __shfl_xor(l, 8);
            const float inv = 1.0f / l;
            const int tt = q0 + w * 16 + quad * 4 + r;
            bf16* yrow = Y + ((size_t)b_ * T_ + tt) * C_ + h_ * HD_;
            for (int nb = 0; nb < 4; ++nb)
                yrow[nb * 16 + fr] = __float2bfloat16(o[nb][r] * inv);
        }
    }
}

extern "C" void kernel_launch(void* const* d_in, const int* in_sizes, int n_in,
                              void* d_out, int out_size, void* d_ws, size_t ws_size,
                              hipStream_t stream) {
    const float* x      = (const float*)d_in[0];
    const float* W_attn = (const float*)d_in[1];
    const float* b_attn = (const float*)d_in[2];
    const float* W_proj = (const float*)d_in[3];
    const float* b_proj = (const float*)d_in[4];
    float* out = (float*)d_out;

    const size_t per = (size_t)B_ * H_ * T_ * HD_;   // 6291456 bf16
    bf16* Q   = (bf16*)d_ws;
    bf16* K   = Q + per;
    bf16* Vt  = K + per;                 // transposed V [B,H,64,T]
    bf16* XbY = Vt + per;                // x-bf16, later attention output Y
    bf16* WaT = XbY + per;
    bf16* WpT = WaT + (size_t)N3_ * C_;

    static bool s_attr = false;
    if (!s_attr) {
        hipFuncSetAttribute((const void*)qkv8p_kernel,
                            hipFuncAttributeMaxDynamicSharedMemorySize, 131072);
        hipFuncSetAttribute((const void*)proj_p_kernel,
                            hipFuncAttributeMaxDynamicSharedMemorySize, 57344);
        s_attr = true;
    }

    cvt_all_kernel<<<dim3(XBLK + WABLK + 576), dim3(256), 0, stream>>>(
        x, XbY, W_attn, WaT, W_proj, WpT);
    qkv8p_kernel<<<dim3(288), dim3(512), 131072, stream>>>(
        XbY, WaT, b_attn, Q, K, Vt);
    flash_attn_kernel<<<dim3(768), dim3(256), 0, stream>>>(Q, K, Vt, XbY);
    proj_p_kernel<<<dim3(512), dim3(256), 57344, stream>>>(
        XbY, WpT, b_proj, out);
}

// Round 8
// 177.916 us; speedup vs baseline: 1.2190x; 1.0684x over previous
//
#include <hip/hip_runtime.h>
#include <hip/hip_bf16.h>

typedef __hip_bfloat16 bf16;
typedef __attribute__((ext_vector_type(8))) short  bfrag;   // 8 bf16 (4 VGPR) MFMA A/B frag
typedef __attribute__((ext_vector_type(4))) float  facc;    // MFMA C/D frag
typedef __attribute__((ext_vector_type(4))) short  short4v; // 4 bf16 = 8B packed store

#define B_   8
#define T_   1024
#define C_   768
#define H_   12
#define HD_  64
#define M_   (B_ * T_)   // 8192
#define N3_  (3 * C_)    // 2304

// Q is stored pre-scaled by 0.125*log2(e) so flash softmax is p = exp2(s - M2)
#define QSCALE_ 0.18033688011112042f
#define M2_     17.312340490667562f

__device__ __forceinline__ float fexp2(float x) { return __builtin_amdgcn_exp2f(x); }

__device__ __forceinline__ void gload_lds16(const bf16* g, bf16* l) {
    __builtin_amdgcn_global_load_lds((const __attribute__((address_space(1))) void*)g,
                                     (__attribute__((address_space(3))) void*)l, 16, 0, 0);
}
__device__ __forceinline__ short bfbits(float f) {
    bf16 b = __float2bfloat16(f);
    return *reinterpret_cast<short*>(&b);
}

#define WAIT_VM(N) asm volatile("s_waitcnt vmcnt(" #N ")" ::: "memory")

// ---------- fused converts: x->bf16, W_attn->bf16^T, W_proj->bf16^T ----------
#define XBLK 6144                       // x: 6291456 / (256*4)
#define WABLK 1728                      // (2304/32)*(768/32)
__global__ __launch_bounds__(256) void cvt_all_kernel(
        const float* __restrict__ x,  bf16* __restrict__ xb,
        const float* __restrict__ wa, bf16* __restrict__ wat,
        const float* __restrict__ wp, bf16* __restrict__ wpt) {
    const int bid = blockIdx.x, t = threadIdx.x;
    if (bid < XBLK) {
        const size_t i = ((size_t)bid * 256 + t) * 4;
        const float4 v = *(const float4*)(x + i);
        bf16* o = xb + i;
        o[0] = __float2bfloat16(v.x); o[1] = __float2bfloat16(v.y);
        o[2] = __float2bfloat16(v.z); o[3] = __float2bfloat16(v.w);
        return;
    }
    __shared__ float tile[32][33];
    const float* w; bf16* wt; int N, tI;
    if (bid < XBLK + WABLK) { w = wa; wt = wat; N = N3_; tI = bid - XBLK; }
    else                    { w = wp; wt = wpt; N = C_;  tI = bid - XBLK - WABLK; }
    const int ntn = N / 32;
    const int n0 = (tI % ntn) * 32, k0 = (tI / ntn) * 32;
    const int tx = t & 31, ty = t >> 5;        // 32 x 8
    for (int i = ty; i < 32; i += 8) tile[i][tx] = w[(size_t)(k0 + i) * N + n0 + tx];
    __syncthreads();
    for (int i = ty; i < 32; i += 8)
        wt[(size_t)(n0 + i) * C_ + k0 + tx] = __float2bfloat16(tile[tx][i]);
}

// ---------- qkv: staggered dbuf GEMM, BM=128, BN=64, 3 blocks/CU ----------
// r4's proven staggered-__syncthreads core (best measured qkv, 44.2us), shrunk
// to BN=64 so LDS = 48KB -> THREE blocks/CU (144KB) = 3 waves/SIMD. The only
// lever that ever moved this kernel was cross-block desync (r4); this doubles
// down on that axis: 12 waves/CU, kt0 = L%12 stagger (co-residents 4-8 tiles
// out of phase), per-XCD 8-row x 36-col chunk keeps working set ~2.8MB < L2.
// __syncthreads (1 per tile) drains the stage issued at loop top (r4 semantics).

template<int NC, bool SWAPPED>          // NC = per-wave col frags (2 -> BN=64)
__device__ __forceinline__ void gemm_s2_core(
        const bf16* __restrict__ Ap, const bf16* __restrict__ Bp,
        const int m0, const int n0, const int kt0,
        bf16* smem, facc (&acc)[4][NC]) {
    constexpr int KD = 768, NT = 12;
    constexpr int BN  = NC * 32;                     // 64
    constexpr int BSZ = BN * 64;                     // elems per B buffer
    constexpr int LB  = BN / 32;                     // B stage passes (2)
    bf16* As = smem;                                 // [2][128*64] = 32 KB
    bf16* Bs = smem + 2 * 8192;                      // [2][BSZ]    = 16 KB
    const int t = threadIdx.x, w = t >> 6, lane = t & 63;
    const int wrow = (w >> 1) * 64;                  // 2 row-waves
    const int wcol = (w & 1) * (NC * 16);            // 2 col-waves
    const int fr = lane & 15, quad = lane >> 4;
    const int pc0 = (quad ^ (fr & 7)) * 8;           // swizzled read chunk, kk=0
    const int pc1 = ((quad + 4) ^ (fr & 7)) * 8;     // kk=1
    const int srow = t >> 3;                         // 0..31 staging row
    const int schunk = ((t & 7) ^ (srow & 7)) * 8;   // swizzled source chunk
    const int sdo = t * 8;                           // linear LDS dest

    const bf16* Ag = Ap + (size_t)(m0 + srow) * KD + schunk;
    const bf16* Bg = Bp + (size_t)(n0 + srow) * KD + schunk;

#pragma unroll
    for (int i = 0; i < 4; ++i)
#pragma unroll
        for (int c = 0; c < NC; ++c)
#pragma unroll
            for (int r = 0; r < 4; ++r) acc[i][c][r] = 0.f;

    auto stageA = [&](bf16* dst, int k0) {           // 4 passes of 32 rows
        const bf16* s = Ag + k0;
        bf16* d = dst + sdo;
#pragma unroll
        for (int r = 0; r < 4; ++r)
            gload_lds16(s + (size_t)(r * 32) * KD, d + r * 2048);
    };
    auto stageB = [&](bf16* dst, int k0) {           // LB passes of 32 rows
        const bf16* s = Bg + k0;
        bf16* d = dst + sdo;
#pragma unroll
        for (int r = 0; r < LB; ++r)
            gload_lds16(s + (size_t)(r * 32) * KD, d + r * 2048);
    };

    // prologue: stage tile kt0
    stageA(As, kt0 * 64);
    stageB(Bs, kt0 * 64);
    __syncthreads();

    int kt = kt0;
#pragma unroll 2
    for (int s = 0; s < NT; ++s) {
        const int cb = s & 1;
        const bf16* AsC = As + cb * 8192;
        const bf16* BsC = Bs + cb * BSZ;
        const int ktn = (kt + 1 == NT) ? 0 : kt + 1;
        // issue next-tile staging FIRST so gloads overlap this tile's compute
        if (s + 1 < NT) {
            stageA(As + (cb ^ 1) * 8192, ktn * 64);
            stageB(Bs + (cb ^ 1) * BSZ,  ktn * 64);
        }
        bfrag af[4][2];
#pragma unroll
        for (int i = 0; i < 4; ++i) {
            const bf16* ar = AsC + (wrow + i * 16 + fr) * 64;
            af[i][0] = *(const bfrag*)(ar + pc0);
            af[i][1] = *(const bfrag*)(ar + pc1);
        }
#pragma unroll
        for (int c = 0; c < NC; ++c) {
            const bf16* br = BsC + (wcol + c * 16 + fr) * 64;
            bfrag b0 = *(const bfrag*)(br + pc0);
            bfrag b1 = *(const bfrag*)(br + pc1);
#pragma unroll
            for (int i = 0; i < 4; ++i) {
                if constexpr (SWAPPED) {
                    acc[i][c] = __builtin_amdgcn_mfma_f32_16x16x32_bf16(b0, af[i][0], acc[i][c], 0, 0, 0);
                    acc[i][c] = __builtin_amdgcn_mfma_f32_16x16x32_bf16(b1, af[i][1], acc[i][c], 0, 0, 0);
                } else {
                    acc[i][c] = __builtin_amdgcn_mfma_f32_16x16x32_bf16(af[i][0], b0, acc[i][c], 0, 0, 0);
                    acc[i][c] = __builtin_amdgcn_mfma_f32_16x16x32_bf16(af[i][1], b1, acc[i][c], 0, 0, 0);
                }
            }
        }
        __syncthreads();   // drains vmcnt+lgkm (stage(t+1) lands); buffer flip
        kt = ktn;
    }
}

// Grid 2304 = 64 by x 36 bx (n0 = bx*64 -> one head per block, clean Q/K/V
// split at bx/12). XCD map: xcd owns by = xcd*8..+7, all 36 bx; L walks
// by-fastest so ~96 concurrent blocks share 12 B-panels + 8 A-panels (~2.8MB).
__global__ __launch_bounds__(256, 3) void qkv64_kernel(
        const bf16* __restrict__ xb, const bf16* __restrict__ wat,
        const float* __restrict__ bias,
        bf16* __restrict__ Q, bf16* __restrict__ K, bf16* __restrict__ Vt) {
    extern __shared__ bf16 smem[];
    const int id = blockIdx.x;
    const int xcd = id & 7, L = id >> 3;           // L in 0..287
    const int by = xcd * 8 + (L & 7), bx = L >> 3; // by 0..63, bx 0..35
    const int m0 = by * 128, n0 = bx * 64;
    const int kt0 = L % 12;                        // anti-convoy K-offset
    const int which = bx / 12;                     // block-uniform: 0=Q 1=K 2=V

    facc acc[4][2];
    if (which < 2) gemm_s2_core<2, true >(xb, wat, m0, n0, kt0, smem, acc);
    else           gemm_s2_core<2, false>(xb, wat, m0, n0, kt0, smem, acc);

    const int t = threadIdx.x, w = t >> 6, lane = t & 63;
    const int wr = (w >> 1) * 64, wc = (w & 1) * 32;
    const int fr = lane & 15, quad = lane >> 4;
    const int bb = m0 >> 10;                       // uniform batch index
    if (which < 2) {
        bf16* dst = which ? K : Q;
        const float sc = which ? 1.0f : QSCALE_;
#pragma unroll
        for (int i = 0; i < 4; ++i) {
            const int tt = (m0 & 1023) + wr + i * 16 + fr;     // token (lane-major)
#pragma unroll
            for (int c = 0; c < 2; ++c) {
                const int colbase = n0 + wc + c * 16 + quad * 4;
                const int cc = colbase - which * C_;
                const int h = cc >> 6, d0 = cc & 63;
                const float4 bv = *(const float4*)(bias + colbase);
                short4v pk;
                pk[0] = bfbits((acc[i][c][0] + bv.x) * sc);
                pk[1] = bfbits((acc[i][c][1] + bv.y) * sc);
                pk[2] = bfbits((acc[i][c][2] + bv.z) * sc);
                pk[3] = bfbits((acc[i][c][3] + bv.w) * sc);
                *(short4v*)(dst + ((size_t)(bb * H_ + h) * T_ + tt) * HD_ + d0) = pk;
            }
        }
    } else {
#pragma unroll
        for (int i = 0; i < 4; ++i) {
            const int tt0 = (m0 & 1023) + wr + i * 16 + quad * 4;  // token, +r over pack
#pragma unroll
            for (int c = 0; c < 2; ++c) {
                const int col = n0 + wc + c * 16 + fr;
                const int cc = col - 2 * C_;
                const int h = cc >> 6, d = cc & 63;
                const float bv = bias[col];
                short4v pk;
                pk[0] = bfbits(acc[i][c][0] + bv);
                pk[1] = bfbits(acc[i][c][1] + bv);
                pk[2] = bfbits(acc[i][c][2] + bv);
                pk[3] = bfbits(acc[i][c][3] + bv);
                *(short4v*)(Vt + ((size_t)(bb * H_ + h) * HD_ + d) * T_ + tt0) = pk;
            }
        }
    }
}

// ---------- proj: r5's counted-vmcnt BN=96 core (best measured proj) ----------
template<bool SWAPPED>
__device__ __forceinline__ void gemm_cv_core(
        const bf16* __restrict__ Ap, const bf16* __restrict__ Bp,
        const int m0, const int n0, const int kt0,
        bf16* smem, facc (&acc)[4][3]) {
    constexpr int KD = 768, NT = 12;
    bf16* As = smem;                      // [2][128*64]
    bf16* Bs = smem + 2 * 8192;           // [2][96*64]
    const int t = threadIdx.x, w = t >> 6, lane = t & 63;
    const int wrow = (w >> 1) * 64;
    const int wcol = (w & 1) * 48;
    const int fr = lane & 15, quad = lane >> 4;
    const int pc0 = (quad ^ (fr & 7)) * 8;
    const int pc1 = ((quad + 4) ^ (fr & 7)) * 8;
    const int srow = t >> 3;
    const int schunk = ((t & 7) ^ (srow & 7)) * 8;
    const int sdo = t * 8;

    const bf16* Ag = Ap + (size_t)(m0 + srow) * KD + schunk;
    const bf16* Bg = Bp + (size_t)(n0 + srow) * KD + schunk;

#pragma unroll
    for (int i = 0; i < 4; ++i)
#pragma unroll
        for (int c = 0; c < 3; ++c)
#pragma unroll
            for (int r = 0; r < 4; ++r) acc[i][c][r] = 0.f;

    auto stageA = [&](bf16* dst, int k0) {
        const bf16* s = Ag + k0;
        bf16* d = dst + sdo;
#pragma unroll
        for (int r = 0; r < 4; ++r)
            gload_lds16(s + (size_t)(r * 32) * KD, d + r * 2048);
    };
    auto stageB = [&](bf16* dst, int k0) {
        const bf16* s = Bg + k0;
        bf16* d = dst + sdo;
#pragma unroll
        for (int r = 0; r < 3; ++r)
            gload_lds16(s + (size_t)(r * 32) * KD, d + r * 2048);
    };

    stageA(As, kt0 * 64);
    stageB(Bs, kt0 * 64);

    int kt = kt0;
#pragma unroll 2
    for (int s = 0; s < NT; ++s) {
        const int cb = s & 1;
        const bf16* AsC = As + cb * 8192;
        const bf16* BsC = Bs + cb * 6144;
        const int ktn = (kt + 1 == NT) ? 0 : kt + 1;
        if (s + 1 < NT) {
            stageA(As + (cb ^ 1) * 8192, ktn * 64);
            stageB(Bs + (cb ^ 1) * 6144, ktn * 64);
            WAIT_VM(7);
        } else {
            WAIT_VM(0);
        }
        __builtin_amdgcn_s_barrier();
        __builtin_amdgcn_sched_barrier(0);
        __builtin_amdgcn_s_setprio(1);
        bfrag af[4][2];
#pragma unroll
        for (int i = 0; i < 4; ++i) {
            const bf16* ar = AsC + (wrow + i * 16 + fr) * 64;
            af[i][0] = *(const bfrag*)(ar + pc0);
            af[i][1] = *(const bfrag*)(ar + pc1);
        }
#pragma unroll
        for (int c = 0; c < 3; ++c) {
            const bf16* br = BsC + (wcol + c * 16 + fr) * 64;
            bfrag b0 = *(const bfrag*)(br + pc0);
            bfrag b1 = *(const bfrag*)(br + pc1);
#pragma unroll
            for (int i = 0; i < 4; ++i) {
                if constexpr (SWAPPED) {
                    acc[i][c] = __builtin_amdgcn_mfma_f32_16x16x32_bf16(b0, af[i][0], acc[i][c], 0, 0, 0);
                    acc[i][c] = __builtin_amdgcn_mfma_f32_16x16x32_bf16(b1, af[i][1], acc[i][c], 0, 0, 0);
                } else {
                    acc[i][c] = __builtin_amdgcn_mfma_f32_16x16x32_bf16(af[i][0], b0, acc[i][c], 0, 0, 0);
                    acc[i][c] = __builtin_amdgcn_mfma_f32_16x16x32_bf16(af[i][1], b1, acc[i][c], 0, 0, 0);
                }
            }
        }
        __builtin_amdgcn_s_setprio(0);
        __builtin_amdgcn_sched_barrier(0);
        __builtin_amdgcn_s_barrier();
        kt = ktn;
    }
}

__global__ __launch_bounds__(256, 2) void proj_p_kernel(
        const bf16* __restrict__ y, const bf16* __restrict__ wpt,
        const float* __restrict__ bias, float* __restrict__ out) {
    extern __shared__ bf16 smem[];
    const int id = blockIdx.x;
    const int xcd = id & 7, L = id >> 3;           // L in 0..63
    const int rgrp = xcd >> 1, cgrp = xcd & 1;
    const int r_l = L & 15, c_l = L >> 4;
    const int by = rgrp * 16 + r_l, bx = cgrp * 4 + c_l;
    const int m0 = by * 128, n0 = bx * 96;
    const int kt0 = L % 12;

    facc acc[4][3];
    gemm_cv_core<true>(y, wpt, m0, n0, kt0, smem, acc);

    const int t = threadIdx.x, w = t >> 6, lane = t & 63;
    const int wr = (w >> 1) * 64, wc = (w & 1) * 48;
    const int fr = lane & 15, quad = lane >> 4;
#pragma unroll
    for (int i = 0; i < 4; ++i) {
        const int row = m0 + wr + i * 16 + fr;
#pragma unroll
        for (int c = 0; c < 3; ++c) {
            const int colbase = n0 + wc + c * 16 + quad * 4;
            const float4 bv = *(const float4*)(bias + colbase);
            float4 v;
            v.x = acc[i][c][0] + bv.x;
            v.y = acc[i][c][1] + bv.y;
            v.z = acc[i][c][2] + bv.z;
            v.w = acc[i][c][3] + bv.w;
            *(float4*)(out + (size_t)row * C_ + colbase) = v;
        }
    }
}

// ---------- flash attention: exp2 static-max softmax + 2 K-tiles per barrier ----------
__global__ __launch_bounds__(256) void flash_attn_kernel(
        const bf16* __restrict__ Q, const bf16* __restrict__ K,
        const bf16* __restrict__ Vt, bf16* __restrict__ Y) {
    const int id   = blockIdx.x;
    const int bh   = (id & 7) * 12 + ((id >> 3) % 12);    // XCD affinity
    const int qpair = (id >> 3) / 12;                     // 0..7
    const int t = threadIdx.x, w = t >> 6, lane = t & 63;
    const int fr = lane & 15, quad = lane >> 4, fq = quad * 8;

    __shared__ bf16 sK[2][64 * 64];
    __shared__ bf16 sVt[2][64 * 64];
    __shared__ bf16 sP[4][16][72];

    const bf16* Kbh = K  + (size_t)bh * T_ * HD_;
    const bf16* Vbh = Vt + (size_t)bh * HD_ * T_;
    const int b_ = bh / H_, h_ = bh % H_;

    const int srow = t >> 3;
    const int sgc  = ((t & 7) ^ (srow & 7)) * 8;
    const int c0   = (quad ^ (fr & 7)) * 8;

    for (int phase = 0; phase < 2; ++phase) {
        const int qt = (phase == 0) ? (15 - qpair) : qpair;
        const int q0 = qt * 64;

        const bf16* qbase = Q + ((size_t)bh * T_ + q0 + w * 16 + fr) * HD_;
        bfrag qa0 = *(const bfrag*)(qbase + fq);
        bfrag qa1 = *(const bfrag*)(qbase + 32 + fq);

        facc o[4];
        for (int nb = 0; nb < 4; ++nb) for (int r = 0; r < 4; ++r) o[nb][r] = 0.f;
        float rowl[4] = {0.f, 0.f, 0.f, 0.f};

        auto tile_step = [&](int kt, const bf16* sKp, const bf16* sVp) {
            const int k0 = kt * 64;
            facc s[4];
            for (int nb = 0; nb < 4; ++nb) for (int r = 0; r < 4; ++r) s[nb][r] = 0.f;
            __builtin_amdgcn_s_setprio(1);
            for (int nb = 0; nb < 4; ++nb) {
                const bf16* kr = sKp + (nb * 16 + fr) * 64;
                bfrag kb0 = *(const bfrag*)(kr + c0);
                bfrag kb1 = *(const bfrag*)(kr + (c0 ^ 32));
                s[nb] = __builtin_amdgcn_mfma_f32_16x16x32_bf16(qa0, kb0, s[nb], 0, 0, 0);
                s[nb] = __builtin_amdgcn_mfma_f32_16x16x32_bf16(qa1, kb1, s[nb], 0, 0, 0);
            }
            __builtin_amdgcn_s_setprio(0);
            const int mrow0 = q0 + w * 16 + quad * 4;
            float p[4][4];
            if (kt == qt) {
                for (int nb = 0; nb < 4; ++nb) {
                    const int n_g = k0 + nb * 16 + fr;
                    for (int r = 0; r < 4; ++r) {
                        const float a = (n_g > mrow0 + r) ? -1e30f : s[nb][r] - M2_;
                        p[nb][r] = fexp2(a);
                    }
                }
            } else {
                for (int nb = 0; nb < 4; ++nb)
                    for (int r = 0; r < 4; ++r)
                        p[nb][r] = fexp2(s[nb][r] - M2_);
            }
            for (int r = 0; r < 4; ++r)
                rowl[r] += p[0][r] + p[1][r] + p[2][r] + p[3][r];
            for (int nb = 0; nb < 4; ++nb)
                for (int r = 0; r < 4; ++r)
                    sP[w][quad * 4 + r][nb * 16 + fr] = __float2bfloat16(p[nb][r]);
            bfrag pa0 = *(const bfrag*)(&sP[w][fr][fq]);
            bfrag pa1 = *(const bfrag*)(&sP[w][fr][32 + fq]);
            __builtin_amdgcn_s_setprio(1);
            for (int nb = 0; nb < 4; ++nb) {
                const bf16* vr = sVp + (nb * 16 + fr) * 64;
                bfrag vb0 = *(const bfrag*)(vr + c0);
                bfrag vb1 = *(const bfrag*)(vr + (c0 ^ 32));
                o[nb] = __builtin_amdgcn_mfma_f32_16x16x32_bf16(pa0, vb0, o[nb], 0, 0, 0);
                o[nb] = __builtin_amdgcn_mfma_f32_16x16x32_bf16(pa1, vb1, o[nb], 0, 0, 0);
            }
            __builtin_amdgcn_s_setprio(0);
        };

        for (int kt = 0; kt <= qt; kt += 2) {
            const int k0 = kt * 64;
            const bool two = (kt + 1 <= qt);
            gload_lds16(Kbh + (size_t)(k0 + srow) * HD_ + sgc,      sK[0] + t * 8);
            gload_lds16(Kbh + (size_t)(k0 + 32 + srow) * HD_ + sgc, sK[0] + 2048 + t * 8);
            gload_lds16(Vbh + (size_t)srow * T_ + k0 + sgc,         sVt[0] + t * 8);
            gload_lds16(Vbh + (size_t)(srow + 32) * T_ + k0 + sgc,  sVt[0] + 2048 + t * 8);
            if (two) {
                const int k1 = k0 + 64;
                gload_lds16(Kbh + (size_t)(k1 + srow) * HD_ + sgc,      sK[1] + t * 8);
                gload_lds16(Kbh + (size_t)(k1 + 32 + srow) * HD_ + sgc, sK[1] + 2048 + t * 8);
                gload_lds16(Vbh + (size_t)srow * T_ + k1 + sgc,         sVt[1] + t * 8);
                gload_lds16(Vbh + (size_t)(srow + 32) * T_ + k1 + sgc,  sVt[1] + 2048 + t * 8);
            }
            __syncthreads();
            tile_step(kt, sK[0], sVt[0]);
            if (two) tile_step(kt + 1, sK[1], sVt[1]);
            __syncthreads();
        }

        for (int r = 0; r < 4; ++r) {
            float l = rowl[r];
            l += __shfl_xor(l, 1);
            l += __shfl_xor(l, 2);
            l += __shfl_xor(l, 4);
            l += __shfl_xor(l, 8);
            const float inv = 1.0f / l;
            const int tt = q0 + w * 16 + quad * 4 + r;
            bf16* yrow = Y + ((size_t)b_ * T_ + tt) * C_ + h_ * HD_;
            for (int nb = 0; nb < 4; ++nb)
                yrow[nb * 16 + fr] = __float2bfloat16(o[nb][r] * inv);
        }
    }
}

extern "C" void kernel_launch(void* const* d_in, const int* in_sizes, int n_in,
                              void* d_out, int out_size, void* d_ws, size_t ws_size,
                              hipStream_t stream) {
    const float* x      = (const float*)d_in[0];
    const float* W_attn = (const float*)d_in[1];
    const float* b_attn = (const float*)d_in[2];
    const float* W_proj = (const float*)d_in[3];
    const float* b_proj = (const float*)d_in[4];
    float* out = (float*)d_out;

    const size_t per = (size_t)B_ * H_ * T_ * HD_;   // 6291456 bf16
    bf16* Q   = (bf16*)d_ws;
    bf16* K   = Q + per;
    bf16* Vt  = K + per;                 // transposed V [B,H,64,T]
    bf16* XbY = Vt + per;                // x-bf16, later attention output Y
    bf16* WaT = XbY + per;
    bf16* WpT = WaT + (size_t)N3_ * C_;

    static bool s_attr = false;
    if (!s_attr) {
        hipFuncSetAttribute((const void*)qkv64_kernel,
                            hipFuncAttributeMaxDynamicSharedMemorySize, 49152);
        hipFuncSetAttribute((const void*)proj_p_kernel,
                            hipFuncAttributeMaxDynamicSharedMemorySize, 57344);
        s_attr = true;
    }

    cvt_all_kernel<<<dim3(XBLK + WABLK + 576), dim3(256), 0, stream>>>(
        x, XbY, W_attn, WaT, W_proj, WpT);
    qkv64_kernel<<<dim3(2304), dim3(256), 49152, stream>>>(
        XbY, WaT, b_attn, Q, K, Vt);
    flash_attn_kernel<<<dim3(768), dim3(256), 0, stream>>>(Q, K, Vt, XbY);
    proj_p_kernel<<<dim3(512), dim3(256), 57344, stream>>>(
        XbY, WpT, b_proj, out);
}

// Round 9
// 176.061 us; speedup vs baseline: 1.2318x; 1.0105x over previous
//
#include <hip/hip_runtime.h>
#include <hip/hip_bf16.h>

typedef __hip_bfloat16 bf16;
typedef __attribute__((ext_vector_type(8))) short  bfrag;   // 8 bf16 (4 VGPR) MFMA A/B frag
typedef __attribute__((ext_vector_type(4))) float  facc;    // MFMA C/D frag
typedef __attribute__((ext_vector_type(4))) short  short4v; // 4 bf16 = 8B packed store

#define B_   8
#define T_   1024
#define C_   768
#define H_   12
#define HD_  64
#define M_   (B_ * T_)   // 8192
#define N3_  (3 * C_)    // 2304

// Q is stored pre-scaled by 0.125*log2(e) so flash softmax is p = exp2(s - M2)
#define QSCALE_ 0.18033688011112042f
#define M2_     17.312340490667562f

__device__ __forceinline__ float fexp2(float x) { return __builtin_amdgcn_exp2f(x); }

__device__ __forceinline__ void gload_lds16(const bf16* g, bf16* l) {
    __builtin_amdgcn_global_load_lds((const __attribute__((address_space(1))) void*)g,
                                     (__attribute__((address_space(3))) void*)l, 16, 0, 0);
}
__device__ __forceinline__ short bfbits(float f) {
    bf16 b = __float2bfloat16(f);
    return *reinterpret_cast<short*>(&b);
}

#define WAIT_VM(N) asm volatile("s_waitcnt vmcnt(" #N ")" ::: "memory")

// ---------- fused converts: x->bf16, W_attn->bf16^T, W_proj->bf16^T ----------
#define XBLK 6144                       // x: 6291456 / (256*4)
#define WABLK 1728                      // (2304/32)*(768/32)
__global__ __launch_bounds__(256) void cvt_all_kernel(
        const float* __restrict__ x,  bf16* __restrict__ xb,
        const float* __restrict__ wa, bf16* __restrict__ wat,
        const float* __restrict__ wp, bf16* __restrict__ wpt) {
    const int bid = blockIdx.x, t = threadIdx.x;
    if (bid < XBLK) {
        const size_t i = ((size_t)bid * 256 + t) * 4;
        const float4 v = *(const float4*)(x + i);
        bf16* o = xb + i;
        o[0] = __float2bfloat16(v.x); o[1] = __float2bfloat16(v.y);
        o[2] = __float2bfloat16(v.z); o[3] = __float2bfloat16(v.w);
        return;
    }
    __shared__ float tile[32][33];
    const float* w; bf16* wt; int N, tI;
    if (bid < XBLK + WABLK) { w = wa; wt = wat; N = N3_; tI = bid - XBLK; }
    else                    { w = wp; wt = wpt; N = C_;  tI = bid - XBLK - WABLK; }
    const int ntn = N / 32;
    const int n0 = (tI % ntn) * 32, k0 = (tI / ntn) * 32;
    const int tx = t & 31, ty = t >> 5;        // 32 x 8
    for (int i = ty; i < 32; i += 8) tile[i][tx] = w[(size_t)(k0 + i) * N + n0 + tx];
    __syncthreads();
    for (int i = ty; i < 32; i += 8)
        wt[(size_t)(n0 + i) * C_ + k0 + tx] = __float2bfloat16(tile[tx][i]);
}

// ---------- qkv: staggered dbuf GEMM, BM=128, BN=64, 3 blocks/CU ----------
// r8 structure unchanged EXCEPT the MFMA issue order: all operand frags are
// loaded first, then all kk0 MFMAs (8 independent), then all kk1. Per-acc
// accumulation order (b0 before b1) is preserved -> bit-identical results;
// dependent-MFMA distance goes 1 -> 8 (MFMA latency ~3-4x issue, so
// back-to-back same-acc pairs stalled the matrix pipe at 2-3 waves/SIMD).

template<int NC, bool SWAPPED>          // NC = per-wave col frags (2 -> BN=64)
__device__ __forceinline__ void gemm_s2_core(
        const bf16* __restrict__ Ap, const bf16* __restrict__ Bp,
        const int m0, const int n0, const int kt0,
        bf16* smem, facc (&acc)[4][NC]) {
    constexpr int KD = 768, NT = 12;
    constexpr int BN  = NC * 32;                     // 64
    constexpr int BSZ = BN * 64;                     // elems per B buffer
    constexpr int LB  = BN / 32;                     // B stage passes (2)
    bf16* As = smem;                                 // [2][128*64] = 32 KB
    bf16* Bs = smem + 2 * 8192;                      // [2][BSZ]    = 16 KB
    const int t = threadIdx.x, w = t >> 6, lane = t & 63;
    const int wrow = (w >> 1) * 64;                  // 2 row-waves
    const int wcol = (w & 1) * (NC * 16);            // 2 col-waves
    const int fr = lane & 15, quad = lane >> 4;
    const int pc0 = (quad ^ (fr & 7)) * 8;           // swizzled read chunk, kk=0
    const int pc1 = ((quad + 4) ^ (fr & 7)) * 8;     // kk=1
    const int srow = t >> 3;                         // 0..31 staging row
    const int schunk = ((t & 7) ^ (srow & 7)) * 8;   // swizzled source chunk
    const int sdo = t * 8;                           // linear LDS dest

    const bf16* Ag = Ap + (size_t)(m0 + srow) * KD + schunk;
    const bf16* Bg = Bp + (size_t)(n0 + srow) * KD + schunk;

#pragma unroll
    for (int i = 0; i < 4; ++i)
#pragma unroll
        for (int c = 0; c < NC; ++c)
#pragma unroll
            for (int r = 0; r < 4; ++r) acc[i][c][r] = 0.f;

    auto stageA = [&](bf16* dst, int k0) {           // 4 passes of 32 rows
        const bf16* s = Ag + k0;
        bf16* d = dst + sdo;
#pragma unroll
        for (int r = 0; r < 4; ++r)
            gload_lds16(s + (size_t)(r * 32) * KD, d + r * 2048);
    };
    auto stageB = [&](bf16* dst, int k0) {           // LB passes of 32 rows
        const bf16* s = Bg + k0;
        bf16* d = dst + sdo;
#pragma unroll
        for (int r = 0; r < LB; ++r)
            gload_lds16(s + (size_t)(r * 32) * KD, d + r * 2048);
    };

    // prologue: stage tile kt0
    stageA(As, kt0 * 64);
    stageB(Bs, kt0 * 64);
    __syncthreads();

    int kt = kt0;
#pragma unroll 2
    for (int s = 0; s < NT; ++s) {
        const int cb = s & 1;
        const bf16* AsC = As + cb * 8192;
        const bf16* BsC = Bs + cb * BSZ;
        const int ktn = (kt + 1 == NT) ? 0 : kt + 1;
        // issue next-tile staging FIRST so gloads overlap this tile's compute
        if (s + 1 < NT) {
            stageA(As + (cb ^ 1) * 8192, ktn * 64);
            stageB(Bs + (cb ^ 1) * BSZ,  ktn * 64);
        }
        bfrag af[4][2], bfr[NC][2];
#pragma unroll
        for (int i = 0; i < 4; ++i) {
            const bf16* ar = AsC + (wrow + i * 16 + fr) * 64;
            af[i][0] = *(const bfrag*)(ar + pc0);
            af[i][1] = *(const bfrag*)(ar + pc1);
        }
#pragma unroll
        for (int c = 0; c < NC; ++c) {
            const bf16* br = BsC + (wcol + c * 16 + fr) * 64;
            bfr[c][0] = *(const bfrag*)(br + pc0);
            bfr[c][1] = *(const bfrag*)(br + pc1);
        }
        // all kk0 (4*NC independent), then all kk1: dep distance 4*NC
#pragma unroll
        for (int c = 0; c < NC; ++c)
#pragma unroll
            for (int i = 0; i < 4; ++i) {
                if constexpr (SWAPPED)
                    acc[i][c] = __builtin_amdgcn_mfma_f32_16x16x32_bf16(bfr[c][0], af[i][0], acc[i][c], 0, 0, 0);
                else
                    acc[i][c] = __builtin_amdgcn_mfma_f32_16x16x32_bf16(af[i][0], bfr[c][0], acc[i][c], 0, 0, 0);
            }
#pragma unroll
        for (int c = 0; c < NC; ++c)
#pragma unroll
            for (int i = 0; i < 4; ++i) {
                if constexpr (SWAPPED)
                    acc[i][c] = __builtin_amdgcn_mfma_f32_16x16x32_bf16(bfr[c][1], af[i][1], acc[i][c], 0, 0, 0);
                else
                    acc[i][c] = __builtin_amdgcn_mfma_f32_16x16x32_bf16(af[i][1], bfr[c][1], acc[i][c], 0, 0, 0);
            }
        __syncthreads();   // drains vmcnt+lgkm (stage(t+1) lands); buffer flip
        kt = ktn;
    }
}

// Grid 2304 = 64 by x 36 bx (n0 = bx*64 -> one head per block, clean Q/K/V
// split at bx/12). XCD map: xcd owns by = xcd*8..+7, all 36 bx.
__global__ __launch_bounds__(256, 3) void qkv64_kernel(
        const bf16* __restrict__ xb, const bf16* __restrict__ wat,
        const float* __restrict__ bias,
        bf16* __restrict__ Q, bf16* __restrict__ K, bf16* __restrict__ Vt) {
    extern __shared__ bf16 smem[];
    const int id = blockIdx.x;
    const int xcd = id & 7, L = id >> 3;           // L in 0..287
    const int by = xcd * 8 + (L & 7), bx = L >> 3; // by 0..63, bx 0..35
    const int m0 = by * 128, n0 = bx * 64;
    const int kt0 = L % 12;                        // anti-convoy K-offset
    const int which = bx / 12;                     // block-uniform: 0=Q 1=K 2=V

    facc acc[4][2];
    if (which < 2) gemm_s2_core<2, true >(xb, wat, m0, n0, kt0, smem, acc);
    else           gemm_s2_core<2, false>(xb, wat, m0, n0, kt0, smem, acc);

    const int t = threadIdx.x, w = t >> 6, lane = t & 63;
    const int wr = (w >> 1) * 64, wc = (w & 1) * 32;
    const int fr = lane & 15, quad = lane >> 4;
    const int bb = m0 >> 10;                       // uniform batch index
    if (which < 2) {
        bf16* dst = which ? K : Q;
        const float sc = which ? 1.0f : QSCALE_;
#pragma unroll
        for (int i = 0; i < 4; ++i) {
            const int tt = (m0 & 1023) + wr + i * 16 + fr;     // token (lane-major)
#pragma unroll
            for (int c = 0; c < 2; ++c) {
                const int colbase = n0 + wc + c * 16 + quad * 4;
                const int cc = colbase - which * C_;
                const int h = cc >> 6, d0 = cc & 63;
                const float4 bv = *(const float4*)(bias + colbase);
                short4v pk;
                pk[0] = bfbits((acc[i][c][0] + bv.x) * sc);
                pk[1] = bfbits((acc[i][c][1] + bv.y) * sc);
                pk[2] = bfbits((acc[i][c][2] + bv.z) * sc);
                pk[3] = bfbits((acc[i][c][3] + bv.w) * sc);
                *(short4v*)(dst + ((size_t)(bb * H_ + h) * T_ + tt) * HD_ + d0) = pk;
            }
        }
    } else {
#pragma unroll
        for (int i = 0; i < 4; ++i) {
            const int tt0 = (m0 & 1023) + wr + i * 16 + quad * 4;  // token, +r over pack
#pragma unroll
            for (int c = 0; c < 2; ++c) {
                const int col = n0 + wc + c * 16 + fr;
                const int cc = col - 2 * C_;
                const int h = cc >> 6, d = cc & 63;
                const float bv = bias[col];
                short4v pk;
                pk[0] = bfbits(acc[i][c][0] + bv);
                pk[1] = bfbits(acc[i][c][1] + bv);
                pk[2] = bfbits(acc[i][c][2] + bv);
                pk[3] = bfbits(acc[i][c][3] + bv);
                *(short4v*)(Vt + ((size_t)(bb * H_ + h) * HD_ + d) * T_ + tt0) = pk;
            }
        }
    }
}

// ---------- proj: r5's counted-vmcnt BN=96 core, MFMA-reordered ----------
template<bool SWAPPED>
__device__ __forceinline__ void gemm_cv_core(
        const bf16* __restrict__ Ap, const bf16* __restrict__ Bp,
        const int m0, const int n0, const int kt0,
        bf16* smem, facc (&acc)[4][3]) {
    constexpr int KD = 768, NT = 12;
    bf16* As = smem;                      // [2][128*64]
    bf16* Bs = smem + 2 * 8192;           // [2][96*64]
    const int t = threadIdx.x, w = t >> 6, lane = t & 63;
    const int wrow = (w >> 1) * 64;
    const int wcol = (w & 1) * 48;
    const int fr = lane & 15, quad = lane >> 4;
    const int pc0 = (quad ^ (fr & 7)) * 8;
    const int pc1 = ((quad + 4) ^ (fr & 7)) * 8;
    const int srow = t >> 3;
    const int schunk = ((t & 7) ^ (srow & 7)) * 8;
    const int sdo = t * 8;

    const bf16* Ag = Ap + (size_t)(m0 + srow) * KD + schunk;
    const bf16* Bg = Bp + (size_t)(n0 + srow) * KD + schunk;

#pragma unroll
    for (int i = 0; i < 4; ++i)
#pragma unroll
        for (int c = 0; c < 3; ++c)
#pragma unroll
            for (int r = 0; r < 4; ++r) acc[i][c][r] = 0.f;

    auto stageA = [&](bf16* dst, int k0) {
        const bf16* s = Ag + k0;
        bf16* d = dst + sdo;
#pragma unroll
        for (int r = 0; r < 4; ++r)
            gload_lds16(s + (size_t)(r * 32) * KD, d + r * 2048);
    };
    auto stageB = [&](bf16* dst, int k0) {
        const bf16* s = Bg + k0;
        bf16* d = dst + sdo;
#pragma unroll
        for (int r = 0; r < 3; ++r)
            gload_lds16(s + (size_t)(r * 32) * KD, d + r * 2048);
    };

    stageA(As, kt0 * 64);
    stageB(Bs, kt0 * 64);

    int kt = kt0;
#pragma unroll 2
    for (int s = 0; s < NT; ++s) {
        const int cb = s & 1;
        const bf16* AsC = As + cb * 8192;
        const bf16* BsC = Bs + cb * 6144;
        const int ktn = (kt + 1 == NT) ? 0 : kt + 1;
        if (s + 1 < NT) {
            stageA(As + (cb ^ 1) * 8192, ktn * 64);
            stageB(Bs + (cb ^ 1) * 6144, ktn * 64);
            WAIT_VM(7);
        } else {
            WAIT_VM(0);
        }
        __builtin_amdgcn_s_barrier();
        __builtin_amdgcn_sched_barrier(0);
        __builtin_amdgcn_s_setprio(1);
        bfrag af[4][2], bfr[3][2];
#pragma unroll
        for (int i = 0; i < 4; ++i) {
            const bf16* ar = AsC + (wrow + i * 16 + fr) * 64;
            af[i][0] = *(const bfrag*)(ar + pc0);
            af[i][1] = *(const bfrag*)(ar + pc1);
        }
#pragma unroll
        for (int c = 0; c < 3; ++c) {
            const bf16* br = BsC + (wcol + c * 16 + fr) * 64;
            bfr[c][0] = *(const bfrag*)(br + pc0);
            bfr[c][1] = *(const bfrag*)(br + pc1);
        }
#pragma unroll
        for (int c = 0; c < 3; ++c)
#pragma unroll
            for (int i = 0; i < 4; ++i) {
                if constexpr (SWAPPED)
                    acc[i][c] = __builtin_amdgcn_mfma_f32_16x16x32_bf16(bfr[c][0], af[i][0], acc[i][c], 0, 0, 0);
                else
                    acc[i][c] = __builtin_amdgcn_mfma_f32_16x16x32_bf16(af[i][0], bfr[c][0], acc[i][c], 0, 0, 0);
            }
#pragma unroll
        for (int c = 0; c < 3; ++c)
#pragma unroll
            for (int i = 0; i < 4; ++i) {
                if constexpr (SWAPPED)
                    acc[i][c] = __builtin_amdgcn_mfma_f32_16x16x32_bf16(bfr[c][1], af[i][1], acc[i][c], 0, 0, 0);
                else
                    acc[i][c] = __builtin_amdgcn_mfma_f32_16x16x32_bf16(af[i][1], bfr[c][1], acc[i][c], 0, 0, 0);
            }
        __builtin_amdgcn_s_setprio(0);
        __builtin_amdgcn_sched_barrier(0);
        __builtin_amdgcn_s_barrier();
        kt = ktn;
    }
}

__global__ __launch_bounds__(256, 2) void proj_p_kernel(
        const bf16* __restrict__ y, const bf16* __restrict__ wpt,
        const float* __restrict__ bias, float* __restrict__ out) {
    extern __shared__ bf16 smem[];
    const int id = blockIdx.x;
    const int xcd = id & 7, L = id >> 3;           // L in 0..63
    const int rgrp = xcd >> 1, cgrp = xcd & 1;
    const int r_l = L & 15, c_l = L >> 4;
    const int by = rgrp * 16 + r_l, bx = cgrp * 4 + c_l;
    const int m0 = by * 128, n0 = bx * 96;
    const int kt0 = L % 12;

    facc acc[4][3];
    gemm_cv_core<true>(y, wpt, m0, n0, kt0, smem, acc);

    const int t = threadIdx.x, w = t >> 6, lane = t & 63;
    const int wr = (w >> 1) * 64, wc = (w & 1) * 48;
    const int fr = lane & 15, quad = lane >> 4;
#pragma unroll
    for (int i = 0; i < 4; ++i) {
        const int row = m0 + wr + i * 16 + fr;
#pragma unroll
        for (int c = 0; c < 3; ++c) {
            const int colbase = n0 + wc + c * 16 + quad * 4;
            const float4 bv = *(const float4*)(bias + colbase);
            float4 v;
            v.x = acc[i][c][0] + bv.x;
            v.y = acc[i][c][1] + bv.y;
            v.z = acc[i][c][2] + bv.z;
            v.w = acc[i][c][3] + bv.w;
            *(float4*)(out + (size_t)row * C_ + colbase) = v;
        }
    }
}

// ---------- flash attention: MERGED two-Q-tile loop ----------
// Each block owns (bh, qpair): Q-tiles qtH = 15-qpair and qtL = qpair
// (qtL < qtH always). Previously the two tiles ran as separate phases,
// staging K/V tiles 0..qtH and 0..qtL -> the prefix 0..qtL was staged TWICE
// (17 tiles/block). Merged: one K-loop 0..qtH stages each tile once
// (16-qpair tiles, avg 12.5, -26%) and runs both tiles' compute inside the
// same barrier window (barrier pairs 9 -> ~6). Epilogues unchanged.
__global__ __launch_bounds__(256, 3) void flash_attn_kernel(
        const bf16* __restrict__ Q, const bf16* __restrict__ K,
        const bf16* __restrict__ Vt, bf16* __restrict__ Y) {
    const int id   = blockIdx.x;
    const int bh   = (id & 7) * 12 + ((id >> 3) % 12);    // XCD affinity
    const int qpair = (id >> 3) / 12;                     // 0..7 (heavy first)
    const int t = threadIdx.x, w = t >> 6, lane = t & 63;
    const int fr = lane & 15, quad = lane >> 4, fq = quad * 8;

    __shared__ bf16 sK[2][64 * 64];       // [buf][key][dim], chunk-swizzled
    __shared__ bf16 sVt[2][64 * 64];      // [buf][dim][key], chunk-swizzled
    __shared__ bf16 sP[4][16][72];        // wave-private P, row stride 72

    const bf16* Kbh = K  + (size_t)bh * T_ * HD_;
    const bf16* Vbh = Vt + (size_t)bh * HD_ * T_;
    const int b_ = bh / H_, h_ = bh % H_;

    const int srow = t >> 3;                                // 0..31 (staging row)
    const int sgc  = ((t & 7) ^ (srow & 7)) * 8;            // swizzled source chunk
    const int c0   = (quad ^ (fr & 7)) * 8;                 // swizzled read chunk

    const int qtH = 15 - qpair, qtL = qpair;
    const int q0H = qtH * 64,  q0L = qtL * 64;

    const bf16* qbH = Q + ((size_t)bh * T_ + q0H + w * 16 + fr) * HD_;
    const bf16* qbL = Q + ((size_t)bh * T_ + q0L + w * 16 + fr) * HD_;
    bfrag qaH0 = *(const bfrag*)(qbH + fq);
    bfrag qaH1 = *(const bfrag*)(qbH + 32 + fq);
    bfrag qaL0 = *(const bfrag*)(qbL + fq);
    bfrag qaL1 = *(const bfrag*)(qbL + 32 + fq);

    facc oH[4], oL[4];
    float rlH[4] = {0.f, 0.f, 0.f, 0.f}, rlL[4] = {0.f, 0.f, 0.f, 0.f};
    for (int nb = 0; nb < 4; ++nb)
        for (int r = 0; r < 4; ++r) { oH[nb][r] = 0.f; oL[nb][r] = 0.f; }

    auto tile_step = [&](int kt, int qt, int q0,
                         const bfrag& qa0, const bfrag& qa1,
                         facc (&o)[4], float (&rowl)[4],
                         const bf16* sKp, const bf16* sVp) {
        const int k0 = kt * 64;
        facc s[4];
        for (int nb = 0; nb < 4; ++nb) for (int r = 0; r < 4; ++r) s[nb][r] = 0.f;
        __builtin_amdgcn_s_setprio(1);                     // T5: favor MFMA wave
        for (int nb = 0; nb < 4; ++nb) {
            const bf16* kr = sKp + (nb * 16 + fr) * 64;
            bfrag kb0 = *(const bfrag*)(kr + c0);
            bfrag kb1 = *(const bfrag*)(kr + (c0 ^ 32));
            s[nb] = __builtin_amdgcn_mfma_f32_16x16x32_bf16(qa0, kb0, s[nb], 0, 0, 0);
            s[nb] = __builtin_amdgcn_mfma_f32_16x16x32_bf16(qa1, kb1, s[nb], 0, 0, 0);
        }
        __builtin_amdgcn_s_setprio(0);
        const int mrow0 = q0 + w * 16 + quad * 4;   // + r
        float p[4][4];
        if (kt == qt) {
            for (int nb = 0; nb < 4; ++nb) {
                const int n_g = k0 + nb * 16 + fr;
                for (int r = 0; r < 4; ++r) {
                    const float a = (n_g > mrow0 + r) ? -1e30f : s[nb][r] - M2_;
                    p[nb][r] = fexp2(a);
                }
            }
        } else {
            for (int nb = 0; nb < 4; ++nb)
                for (int r = 0; r < 4; ++r)
                    p[nb][r] = fexp2(s[nb][r] - M2_);
        }
        for (int r = 0; r < 4; ++r)
            rowl[r] += p[0][r] + p[1][r] + p[2][r] + p[3][r];
        for (int nb = 0; nb < 4; ++nb)
            for (int r = 0; r < 4; ++r)
                sP[w][quad * 4 + r][nb * 16 + fr] = __float2bfloat16(p[nb][r]);
        bfrag pa0 = *(const bfrag*)(&sP[w][fr][fq]);
        bfrag pa1 = *(const bfrag*)(&sP[w][fr][32 + fq]);
        __builtin_amdgcn_s_setprio(1);                     // T5: favor MFMA wave
        for (int nb = 0; nb < 4; ++nb) {
            const bf16* vr = sVp + (nb * 16 + fr) * 64;
            bfrag vb0 = *(const bfrag*)(vr + c0);
            bfrag vb1 = *(const bfrag*)(vr + (c0 ^ 32));
            o[nb] = __builtin_amdgcn_mfma_f32_16x16x32_bf16(pa0, vb0, o[nb], 0, 0, 0);
            o[nb] = __builtin_amdgcn_mfma_f32_16x16x32_bf16(pa1, vb1, o[nb], 0, 0, 0);
        }
        __builtin_amdgcn_s_setprio(0);
    };

    for (int kt = 0; kt <= qtH; kt += 2) {
        const int k0 = kt * 64;
        const bool two = (kt + 1 <= qtH);
        gload_lds16(Kbh + (size_t)(k0 + srow) * HD_ + sgc,      sK[0] + t * 8);
        gload_lds16(Kbh + (size_t)(k0 + 32 + srow) * HD_ + sgc, sK[0] + 2048 + t * 8);
        gload_lds16(Vbh + (size_t)srow * T_ + k0 + sgc,         sVt[0] + t * 8);
        gload_lds16(Vbh + (size_t)(srow + 32) * T_ + k0 + sgc,  sVt[0] + 2048 + t * 8);
        if (two) {
            const int k1 = k0 + 64;
            gload_lds16(Kbh + (size_t)(k1 + srow) * HD_ + sgc,      sK[1] + t * 8);
            gload_lds16(Kbh + (size_t)(k1 + 32 + srow) * HD_ + sgc, sK[1] + 2048 + t * 8);
            gload_lds16(Vbh + (size_t)srow * T_ + k1 + sgc,         sVt[1] + t * 8);
            gload_lds16(Vbh + (size_t)(srow + 32) * T_ + k1 + sgc,  sVt[1] + 2048 + t * 8);
        }
        __syncthreads();
        tile_step(kt, qtH, q0H, qaH0, qaH1, oH, rlH, sK[0], sVt[0]);
        if (kt <= qtL)
            tile_step(kt, qtL, q0L, qaL0, qaL1, oL, rlL, sK[0], sVt[0]);
        if (two) {
            tile_step(kt + 1, qtH, q0H, qaH0, qaH1, oH, rlH, sK[1], sVt[1]);
            if (kt + 1 <= qtL)
                tile_step(kt + 1, qtL, q0L, qaL0, qaL1, oL, rlL, sK[1], sVt[1]);
        }
        __syncthreads();
    }

    // epilogues (H then L)
#pragma unroll
    for (int e = 0; e < 2; ++e) {
        facc* o = e ? oL : oH;
        float* rowl = e ? rlL : rlH;
        const int q0 = e ? q0L : q0H;
        for (int r = 0; r < 4; ++r) {
            float l = rowl[r];
            l += __shfl_xor(l, 1);
            l += __shfl_xor(l, 2);
            l += __shfl_xor(l, 4);
            l += __shfl_xor(l, 8);
            const float inv = 1.0f / l;
            const int tt = q0 + w * 16 + quad * 4 + r;
            bf16* yrow = Y + ((size_t)b_ * T_ + tt) * C_ + h_ * HD_;
            for (int nb = 0; nb < 4; ++nb)
                yrow[nb * 16 + fr] = __float2bfloat16(o[nb][r] * inv);
        }
    }
}

extern "C" void kernel_launch(void* const* d_in, const int* in_sizes, int n_in,
                              void* d_out, int out_size, void* d_ws, size_t ws_size,
                              hipStream_t stream) {
    const float* x      = (const float*)d_in[0];
    const float* W_attn = (const float*)d_in[1];
    const float* b_attn = (const float*)d_in[2];
    const float* W_proj = (const float*)d_in[3];
    const float* b_proj = (const float*)d_in[4];
    float* out = (float*)d_out;

    const size_t per = (size_t)B_ * H_ * T_ * HD_;   // 6291456 bf16
    bf16* Q   = (bf16*)d_ws;
    bf16* K   = Q + per;
    bf16* Vt  = K + per;                 // transposed V [B,H,64,T]
    bf16* XbY = Vt + per;                // x-bf16, later attention output Y
    bf16* WaT = XbY + per;
    bf16* WpT = WaT + (size_t)N3_ * C_;

    static bool s_attr = false;
    if (!s_attr) {
        hipFuncSetAttribute((const void*)qkv64_kernel,
                            hipFuncAttributeMaxDynamicSharedMemorySize, 49152);
        hipFuncSetAttribute((const void*)proj_p_kernel,
                            hipFuncAttributeMaxDynamicSharedMemorySize, 57344);
        s_attr = true;
    }

    cvt_all_kernel<<<dim3(XBLK + WABLK + 576), dim3(256), 0, stream>>>(
        x, XbY, W_attn, WaT, W_proj, WpT);
    qkv64_kernel<<<dim3(2304), dim3(256), 49152, stream>>>(
        XbY, WaT, b_attn, Q, K, Vt);
    flash_attn_kernel<<<dim3(768), dim3(256), 0, stream>>>(Q, K, Vt, XbY);
    proj_p_kernel<<<dim3(512), dim3(256), 57344, stream>>>(
        XbY, WpT, b_proj, out);
}

// Round 10
// 174.432 us; speedup vs baseline: 1.2433x; 1.0093x over previous
//
#include <hip/hip_runtime.h>
#include <hip/hip_bf16.h>

typedef __hip_bfloat16 bf16;
typedef __attribute__((ext_vector_type(8))) short  bfrag;   // 8 bf16 (4 VGPR) MFMA A/B frag
typedef __attribute__((ext_vector_type(4))) float  facc;    // MFMA C/D frag
typedef __attribute__((ext_vector_type(4))) short  short4v; // 4 bf16 = 8B packed store

#define B_   8
#define T_   1024
#define C_   768
#define H_   12
#define HD_  64
#define M_   (B_ * T_)   // 8192
#define N3_  (3 * C_)    // 2304

// Q is stored pre-scaled by 0.125*log2(e) so flash softmax is p = exp2(s - M2)
#define QSCALE_ 0.18033688011112042f
#define M2_     17.312340490667562f

__device__ __forceinline__ float fexp2(float x) { return __builtin_amdgcn_exp2f(x); }

__device__ __forceinline__ void gload_lds16(const bf16* g, bf16* l) {
    __builtin_amdgcn_global_load_lds((const __attribute__((address_space(1))) void*)g,
                                     (__attribute__((address_space(3))) void*)l, 16, 0, 0);
}
__device__ __forceinline__ short bfbits(float f) {
    bf16 b = __float2bfloat16(f);
    return *reinterpret_cast<short*>(&b);
}

#define WAIT_VM(N) asm volatile("s_waitcnt vmcnt(" #N ")" ::: "memory")

// ---------- fused converts, FULLY VECTORIZED (G13: no scalar bf16 stores) ----
// x path: 8 floats/thread -> one 16B bf16x8 store (was 4x2B scalar stores).
// weight path: transpose via LDS, write 8 bf16 per 16B store (was scalar).
#define XV 3072                         // x: 6291456 / (256*8)
#define WABLK 1728                      // (2304/32)*(768/32)
__global__ __launch_bounds__(256) void cvt_vec_kernel(
        const float* __restrict__ x,  bf16* __restrict__ xb,
        const float* __restrict__ wa, bf16* __restrict__ wat,
        const float* __restrict__ wp, bf16* __restrict__ wpt) {
    const int bid = blockIdx.x, t = threadIdx.x;
    if (bid < XV) {
        const size_t i = ((size_t)bid * 256 + t) * 8;
        const float4 v0 = *(const float4*)(x + i);
        const float4 v1 = *(const float4*)(x + i + 4);
        bfrag v;
        v[0] = bfbits(v0.x); v[1] = bfbits(v0.y); v[2] = bfbits(v0.z); v[3] = bfbits(v0.w);
        v[4] = bfbits(v1.x); v[5] = bfbits(v1.y); v[6] = bfbits(v1.z); v[7] = bfbits(v1.w);
        *(bfrag*)((unsigned short*)xb + i) = v;
        return;
    }
    __shared__ float tile[32][33];      // tile[k_local][n_local]
    const float* w; bf16* wt; int N, tI;
    if (bid < XV + WABLK) { w = wa; wt = wat; N = N3_; tI = bid - XV; }
    else                  { w = wp; wt = wpt; N = C_;  tI = bid - XV - WABLK; }
    const int ntn = N / 32;
    const int n0 = (tI % ntn) * 32, k0 = (tI / ntn) * 32;
    const int tx = t & 31, ty = t >> 5;        // 32 x 8 load layout
    for (int i = ty; i < 32; i += 8) tile[i][tx] = w[(size_t)(k0 + i) * N + n0 + tx];
    __syncthreads();
    if (t < 128) {                             // 32 out-rows x 4 chunks of 8
        const int r = t >> 2, ch = t & 3;
        bfrag v;
#pragma unroll
        for (int j = 0; j < 8; ++j) v[j] = bfbits(tile[ch * 8 + j][r]);
        *(bfrag*)((unsigned short*)wt + (size_t)(n0 + r) * C_ + k0 + ch * 8) = v;
    }
}

// ---------- qkv: staggered dbuf GEMM, BM=128, BN=64, 3 blocks/CU (r9 best) ----
template<int NC, bool SWAPPED>          // NC = per-wave col frags (2 -> BN=64)
__device__ __forceinline__ void gemm_s2_core(
        const bf16* __restrict__ Ap, const bf16* __restrict__ Bp,
        const int m0, const int n0, const int kt0,
        bf16* smem, facc (&acc)[4][NC]) {
    constexpr int KD = 768, NT = 12;
    constexpr int BN  = NC * 32;                     // 64
    constexpr int BSZ = BN * 64;                     // elems per B buffer
    constexpr int LB  = BN / 32;                     // B stage passes (2)
    bf16* As = smem;                                 // [2][128*64] = 32 KB
    bf16* Bs = smem + 2 * 8192;                      // [2][BSZ]    = 16 KB
    const int t = threadIdx.x, w = t >> 6, lane = t & 63;
    const int wrow = (w >> 1) * 64;                  // 2 row-waves
    const int wcol = (w & 1) * (NC * 16);            // 2 col-waves
    const int fr = lane & 15, quad = lane >> 4;
    const int pc0 = (quad ^ (fr & 7)) * 8;           // swizzled read chunk, kk=0
    const int pc1 = ((quad + 4) ^ (fr & 7)) * 8;     // kk=1
    const int srow = t >> 3;                         // 0..31 staging row
    const int schunk = ((t & 7) ^ (srow & 7)) * 8;   // swizzled source chunk
    const int sdo = t * 8;                           // linear LDS dest

    const bf16* Ag = Ap + (size_t)(m0 + srow) * KD + schunk;
    const bf16* Bg = Bp + (size_t)(n0 + srow) * KD + schunk;

#pragma unroll
    for (int i = 0; i < 4; ++i)
#pragma unroll
        for (int c = 0; c < NC; ++c)
#pragma unroll
            for (int r = 0; r < 4; ++r) acc[i][c][r] = 0.f;

    auto stageA = [&](bf16* dst, int k0) {           // 4 passes of 32 rows
        const bf16* s = Ag + k0;
        bf16* d = dst + sdo;
#pragma unroll
        for (int r = 0; r < 4; ++r)
            gload_lds16(s + (size_t)(r * 32) * KD, d + r * 2048);
    };
    auto stageB = [&](bf16* dst, int k0) {           // LB passes of 32 rows
        const bf16* s = Bg + k0;
        bf16* d = dst + sdo;
#pragma unroll
        for (int r = 0; r < LB; ++r)
            gload_lds16(s + (size_t)(r * 32) * KD, d + r * 2048);
    };

    // prologue: stage tile kt0
    stageA(As, kt0 * 64);
    stageB(Bs, kt0 * 64);
    __syncthreads();

    int kt = kt0;
#pragma unroll 2
    for (int s = 0; s < NT; ++s) {
        const int cb = s & 1;
        const bf16* AsC = As + cb * 8192;
        const bf16* BsC = Bs + cb * BSZ;
        const int ktn = (kt + 1 == NT) ? 0 : kt + 1;
        // issue next-tile staging FIRST so gloads overlap this tile's compute
        if (s + 1 < NT) {
            stageA(As + (cb ^ 1) * 8192, ktn * 64);
            stageB(Bs + (cb ^ 1) * BSZ,  ktn * 64);
        }
        bfrag af[4][2], bfr[NC][2];
#pragma unroll
        for (int i = 0; i < 4; ++i) {
            const bf16* ar = AsC + (wrow + i * 16 + fr) * 64;
            af[i][0] = *(const bfrag*)(ar + pc0);
            af[i][1] = *(const bfrag*)(ar + pc1);
        }
#pragma unroll
        for (int c = 0; c < NC; ++c) {
            const bf16* br = BsC + (wcol + c * 16 + fr) * 64;
            bfr[c][0] = *(const bfrag*)(br + pc0);
            bfr[c][1] = *(const bfrag*)(br + pc1);
        }
        // all kk0 (4*NC independent), then all kk1: dep distance 4*NC
#pragma unroll
        for (int c = 0; c < NC; ++c)
#pragma unroll
            for (int i = 0; i < 4; ++i) {
                if constexpr (SWAPPED)
                    acc[i][c] = __builtin_amdgcn_mfma_f32_16x16x32_bf16(bfr[c][0], af[i][0], acc[i][c], 0, 0, 0);
                else
                    acc[i][c] = __builtin_amdgcn_mfma_f32_16x16x32_bf16(af[i][0], bfr[c][0], acc[i][c], 0, 0, 0);
            }
#pragma unroll
        for (int c = 0; c < NC; ++c)
#pragma unroll
            for (int i = 0; i < 4; ++i) {
                if constexpr (SWAPPED)
                    acc[i][c] = __builtin_amdgcn_mfma_f32_16x16x32_bf16(bfr[c][1], af[i][1], acc[i][c], 0, 0, 0);
                else
                    acc[i][c] = __builtin_amdgcn_mfma_f32_16x16x32_bf16(af[i][1], bfr[c][1], acc[i][c], 0, 0, 0);
            }
        __syncthreads();   // drains vmcnt+lgkm (stage(t+1) lands); buffer flip
        kt = ktn;
    }
}

// Grid 2304 = 64 by x 36 bx (n0 = bx*64 -> one head per block, clean Q/K/V
// split at bx/12). XCD map: xcd owns by = xcd*8..+7, all 36 bx.
__global__ __launch_bounds__(256, 3) void qkv64_kernel(
        const bf16* __restrict__ xb, const bf16* __restrict__ wat,
        const float* __restrict__ bias,
        bf16* __restrict__ Q, bf16* __restrict__ K, bf16* __restrict__ Vt) {
    extern __shared__ bf16 smem[];
    const int id = blockIdx.x;
    const int xcd = id & 7, L = id >> 3;           // L in 0..287
    const int by = xcd * 8 + (L & 7), bx = L >> 3; // by 0..63, bx 0..35
    const int m0 = by * 128, n0 = bx * 64;
    const int kt0 = L % 12;                        // anti-convoy K-offset
    const int which = bx / 12;                     // block-uniform: 0=Q 1=K 2=V

    facc acc[4][2];
    if (which < 2) gemm_s2_core<2, true >(xb, wat, m0, n0, kt0, smem, acc);
    else           gemm_s2_core<2, false>(xb, wat, m0, n0, kt0, smem, acc);

    const int t = threadIdx.x, w = t >> 6, lane = t & 63;
    const int wr = (w >> 1) * 64, wc = (w & 1) * 32;
    const int fr = lane & 15, quad = lane >> 4;
    const int bb = m0 >> 10;                       // uniform batch index
    if (which < 2) {
        bf16* dst = which ? K : Q;
        const float sc = which ? 1.0f : QSCALE_;
#pragma unroll
        for (int i = 0; i < 4; ++i) {
            const int tt = (m0 & 1023) + wr + i * 16 + fr;     // token (lane-major)
#pragma unroll
            for (int c = 0; c < 2; ++c) {
                const int colbase = n0 + wc + c * 16 + quad * 4;
                const int cc = colbase - which * C_;
                const int h = cc >> 6, d0 = cc & 63;
                const float4 bv = *(const float4*)(bias + colbase);
                short4v pk;
                pk[0] = bfbits((acc[i][c][0] + bv.x) * sc);
                pk[1] = bfbits((acc[i][c][1] + bv.y) * sc);
                pk[2] = bfbits((acc[i][c][2] + bv.z) * sc);
                pk[3] = bfbits((acc[i][c][3] + bv.w) * sc);
                *(short4v*)(dst + ((size_t)(bb * H_ + h) * T_ + tt) * HD_ + d0) = pk;
            }
        }
    } else {
#pragma unroll
        for (int i = 0; i < 4; ++i) {
            const int tt0 = (m0 & 1023) + wr + i * 16 + quad * 4;  // token, +r over pack
#pragma unroll
            for (int c = 0; c < 2; ++c) {
                const int col = n0 + wc + c * 16 + fr;
                const int cc = col - 2 * C_;
                const int h = cc >> 6, d = cc & 63;
                const float bv = bias[col];
                short4v pk;
                pk[0] = bfbits(acc[i][c][0] + bv);
                pk[1] = bfbits(acc[i][c][1] + bv);
                pk[2] = bfbits(acc[i][c][2] + bv);
                pk[3] = bfbits(acc[i][c][3] + bv);
                *(short4v*)(Vt + ((size_t)(bb * H_ + h) * HD_ + d) * T_ + tt0) = pk;
            }
        }
    }
}

// ---------- proj: counted-vmcnt BN=96 core, MFMA-reordered (r9) ----------
template<bool SWAPPED>
__device__ __forceinline__ void gemm_cv_core(
        const bf16* __restrict__ Ap, const bf16* __restrict__ Bp,
        const int m0, const int n0, const int kt0,
        bf16* smem, facc (&acc)[4][3]) {
    constexpr int KD = 768, NT = 12;
    bf16* As = smem;                      // [2][128*64]
    bf16* Bs = smem + 2 * 8192;           // [2][96*64]
    const int t = threadIdx.x, w = t >> 6, lane = t & 63;
    const int wrow = (w >> 1) * 64;
    const int wcol = (w & 1) * 48;
    const int fr = lane & 15, quad = lane >> 4;
    const int pc0 = (quad ^ (fr & 7)) * 8;
    const int pc1 = ((quad + 4) ^ (fr & 7)) * 8;
    const int srow = t >> 3;
    const int schunk = ((t & 7) ^ (srow & 7)) * 8;
    const int sdo = t * 8;

    const bf16* Ag = Ap + (size_t)(m0 + srow) * KD + schunk;
    const bf16* Bg = Bp + (size_t)(n0 + srow) * KD + schunk;

#pragma unroll
    for (int i = 0; i < 4; ++i)
#pragma unroll
        for (int c = 0; c < 3; ++c)
#pragma unroll
            for (int r = 0; r < 4; ++r) acc[i][c][r] = 0.f;

    auto stageA = [&](bf16* dst, int k0) {
        const bf16* s = Ag + k0;
        bf16* d = dst + sdo;
#pragma unroll
        for (int r = 0; r < 4; ++r)
            gload_lds16(s + (size_t)(r * 32) * KD, d + r * 2048);
    };
    auto stageB = [&](bf16* dst, int k0) {
        const bf16* s = Bg + k0;
        bf16* d = dst + sdo;
#pragma unroll
        for (int r = 0; r < 3; ++r)
            gload_lds16(s + (size_t)(r * 32) * KD, d + r * 2048);
    };

    stageA(As, kt0 * 64);
    stageB(Bs, kt0 * 64);

    int kt = kt0;
#pragma unroll 2
    for (int s = 0; s < NT; ++s) {
        const int cb = s & 1;
        const bf16* AsC = As + cb * 8192;
        const bf16* BsC = Bs + cb * 6144;
        const int ktn = (kt + 1 == NT) ? 0 : kt + 1;
        if (s + 1 < NT) {
            stageA(As + (cb ^ 1) * 8192, ktn * 64);
            stageB(Bs + (cb ^ 1) * 6144, ktn * 64);
            WAIT_VM(7);
        } else {
            WAIT_VM(0);
        }
        __builtin_amdgcn_s_barrier();
        __builtin_amdgcn_sched_barrier(0);
        __builtin_amdgcn_s_setprio(1);
        bfrag af[4][2], bfr[3][2];
#pragma unroll
        for (int i = 0; i < 4; ++i) {
            const bf16* ar = AsC + (wrow + i * 16 + fr) * 64;
            af[i][0] = *(const bfrag*)(ar + pc0);
            af[i][1] = *(const bfrag*)(ar + pc1);
        }
#pragma unroll
        for (int c = 0; c < 3; ++c) {
            const bf16* br = BsC + (wcol + c * 16 + fr) * 64;
            bfr[c][0] = *(const bfrag*)(br + pc0);
            bfr[c][1] = *(const bfrag*)(br + pc1);
        }
#pragma unroll
        for (int c = 0; c < 3; ++c)
#pragma unroll
            for (int i = 0; i < 4; ++i) {
                if constexpr (SWAPPED)
                    acc[i][c] = __builtin_amdgcn_mfma_f32_16x16x32_bf16(bfr[c][0], af[i][0], acc[i][c], 0, 0, 0);
                else
                    acc[i][c] = __builtin_amdgcn_mfma_f32_16x16x32_bf16(af[i][0], bfr[c][0], acc[i][c], 0, 0, 0);
            }
#pragma unroll
        for (int c = 0; c < 3; ++c)
#pragma unroll
            for (int i = 0; i < 4; ++i) {
                if constexpr (SWAPPED)
                    acc[i][c] = __builtin_amdgcn_mfma_f32_16x16x32_bf16(bfr[c][1], af[i][1], acc[i][c], 0, 0, 0);
                else
                    acc[i][c] = __builtin_amdgcn_mfma_f32_16x16x32_bf16(af[i][1], bfr[c][1], acc[i][c], 0, 0, 0);
            }
        __builtin_amdgcn_s_setprio(0);
        __builtin_amdgcn_sched_barrier(0);
        __builtin_amdgcn_s_barrier();
        kt = ktn;
    }
}

__global__ __launch_bounds__(256, 2) void proj_p_kernel(
        const bf16* __restrict__ y, const bf16* __restrict__ wpt,
        const float* __restrict__ bias, float* __restrict__ out) {
    extern __shared__ bf16 smem[];
    const int id = blockIdx.x;
    const int xcd = id & 7, L = id >> 3;           // L in 0..63
    const int rgrp = xcd >> 1, cgrp = xcd & 1;
    const int r_l = L & 15, c_l = L >> 4;
    const int by = rgrp * 16 + r_l, bx = cgrp * 4 + c_l;
    const int m0 = by * 128, n0 = bx * 96;
    const int kt0 = L % 12;

    facc acc[4][3];
    gemm_cv_core<true>(y, wpt, m0, n0, kt0, smem, acc);

    const int t = threadIdx.x, w = t >> 6, lane = t & 63;
    const int wr = (w >> 1) * 64, wc = (w & 1) * 48;
    const int fr = lane & 15, quad = lane >> 4;
#pragma unroll
    for (int i = 0; i < 4; ++i) {
        const int row = m0 + wr + i * 16 + fr;
#pragma unroll
        for (int c = 0; c < 3; ++c) {
            const int colbase = n0 + wc + c * 16 + quad * 4;
            const float4 bv = *(const float4*)(bias + colbase);
            float4 v;
            v.x = acc[i][c][0] + bv.x;
            v.y = acc[i][c][1] + bv.y;
            v.z = acc[i][c][2] + bv.z;
            v.w = acc[i][c][3] + bv.w;
            *(float4*)(out + (size_t)row * C_ + colbase) = v;
        }
    }
}

// ---------- flash attention: MERGED two-Q-tile loop (r9) ----------
__global__ __launch_bounds__(256, 3) void flash_attn_kernel(
        const bf16* __restrict__ Q, const bf16* __restrict__ K,
        const bf16* __restrict__ Vt, bf16* __restrict__ Y) {
    const int id   = blockIdx.x;
    const int bh   = (id & 7) * 12 + ((id >> 3) % 12);    // XCD affinity
    const int qpair = (id >> 3) / 12;                     // 0..7 (heavy first)
    const int t = threadIdx.x, w = t >> 6, lane = t & 63;
    const int fr = lane & 15, quad = lane >> 4, fq = quad * 8;

    __shared__ bf16 sK[2][64 * 64];       // [buf][key][dim], chunk-swizzled
    __shared__ bf16 sVt[2][64 * 64];      // [buf][dim][key], chunk-swizzled
    __shared__ bf16 sP[4][16][72];        // wave-private P, row stride 72

    const bf16* Kbh = K  + (size_t)bh * T_ * HD_;
    const bf16* Vbh = Vt + (size_t)bh * HD_ * T_;
    const int b_ = bh / H_, h_ = bh % H_;

    const int srow = t >> 3;                                // 0..31 (staging row)
    const int sgc  = ((t & 7) ^ (srow & 7)) * 8;            // swizzled source chunk
    const int c0   = (quad ^ (fr & 7)) * 8;                 // swizzled read chunk

    const int qtH = 15 - qpair, qtL = qpair;
    const int q0H = qtH * 64,  q0L = qtL * 64;

    const bf16* qbH = Q + ((size_t)bh * T_ + q0H + w * 16 + fr) * HD_;
    const bf16* qbL = Q + ((size_t)bh * T_ + q0L + w * 16 + fr) * HD_;
    bfrag qaH0 = *(const bfrag*)(qbH + fq);
    bfrag qaH1 = *(const bfrag*)(qbH + 32 + fq);
    bfrag qaL0 = *(const bfrag*)(qbL + fq);
    bfrag qaL1 = *(const bfrag*)(qbL + 32 + fq);

    facc oH[4], oL[4];
    float rlH[4] = {0.f, 0.f, 0.f, 0.f}, rlL[4] = {0.f, 0.f, 0.f, 0.f};
    for (int nb = 0; nb < 4; ++nb)
        for (int r = 0; r < 4; ++r) { oH[nb][r] = 0.f; oL[nb][r] = 0.f; }

    auto tile_step = [&](int kt, int qt, int q0,
                         const bfrag& qa0, const bfrag& qa1,
                         facc (&o)[4], float (&rowl)[4],
                         const bf16* sKp, const bf16* sVp) {
        const int k0 = kt * 64;
        facc s[4];
        for (int nb = 0; nb < 4; ++nb) for (int r = 0; r < 4; ++r) s[nb][r] = 0.f;
        __builtin_amdgcn_s_setprio(1);                     // T5: favor MFMA wave
        for (int nb = 0; nb < 4; ++nb) {
            const bf16* kr = sKp + (nb * 16 + fr) * 64;
            bfrag kb0 = *(const bfrag*)(kr + c0);
            bfrag kb1 = *(const bfrag*)(kr + (c0 ^ 32));
            s[nb] = __builtin_amdgcn_mfma_f32_16x16x32_bf16(qa0, kb0, s[nb], 0, 0, 0);
            s[nb] = __builtin_amdgcn_mfma_f32_16x16x32_bf16(qa1, kb1, s[nb], 0, 0, 0);
        }
        __builtin_amdgcn_s_setprio(0);
        const int mrow0 = q0 + w * 16 + quad * 4;   // + r
        float p[4][4];
        if (kt == qt) {
            for (int nb = 0; nb < 4; ++nb) {
                const int n_g = k0 + nb * 16 + fr;
                for (int r = 0; r < 4; ++r) {
                    const float a = (n_g > mrow0 + r) ? -1e30f : s[nb][r] - M2_;
                    p[nb][r] = fexp2(a);
                }
            }
        } else {
            for (int nb = 0; nb < 4; ++nb)
                for (int r = 0; r < 4; ++r)
                    p[nb][r] = fexp2(s[nb][r] - M2_);
        }
        for (int r = 0; r < 4; ++r)
            rowl[r] += p[0][r] + p[1][r] + p[2][r] + p[3][r];
        for (int nb = 0; nb < 4; ++nb)
            for (int r = 0; r < 4; ++r)
                sP[w][quad * 4 + r][nb * 16 + fr] = __float2bfloat16(p[nb][r]);
        bfrag pa0 = *(const bfrag*)(&sP[w][fr][fq]);
        bfrag pa1 = *(const bfrag*)(&sP[w][fr][32 + fq]);
        __builtin_amdgcn_s_setprio(1);                     // T5: favor MFMA wave
        for (int nb = 0; nb < 4; ++nb) {
            const bf16* vr = sVp + (nb * 16 + fr) * 64;
            bfrag vb0 = *(const bfrag*)(vr + c0);
            bfrag vb1 = *(const bfrag*)(vr + (c0 ^ 32));
            o[nb] = __builtin_amdgcn_mfma_f32_16x16x32_bf16(pa0, vb0, o[nb], 0, 0, 0);
            o[nb] = __builtin_amdgcn_mfma_f32_16x16x32_bf16(pa1, vb1, o[nb], 0, 0, 0);
        }
        __builtin_amdgcn_s_setprio(0);
    };

    for (int kt = 0; kt <= qtH; kt += 2) {
        const int k0 = kt * 64;
        const bool two = (kt + 1 <= qtH);
        gload_lds16(Kbh + (size_t)(k0 + srow) * HD_ + sgc,      sK[0] + t * 8);
        gload_lds16(Kbh + (size_t)(k0 + 32 + srow) * HD_ + sgc, sK[0] + 2048 + t * 8);
        gload_lds16(Vbh + (size_t)srow * T_ + k0 + sgc,         sVt[0] + t * 8);
        gload_lds16(Vbh + (size_t)(srow + 32) * T_ + k0 + sgc,  sVt[0] + 2048 + t * 8);
        if (two) {
            const int k1 = k0 + 64;
            gload_lds16(Kbh + (size_t)(k1 + srow) * HD_ + sgc,      sK[1] + t * 8);
            gload_lds16(Kbh + (size_t)(k1 + 32 + srow) * HD_ + sgc, sK[1] + 2048 + t * 8);
            gload_lds16(Vbh + (size_t)srow * T_ + k1 + sgc,         sVt[1] + t * 8);
            gload_lds16(Vbh + (size_t)(srow + 32) * T_ + k1 + sgc,  sVt[1] + 2048 + t * 8);
        }
        __syncthreads();
        tile_step(kt, qtH, q0H, qaH0, qaH1, oH, rlH, sK[0], sVt[0]);
        if (kt <= qtL)
            tile_step(kt, qtL, q0L, qaL0, qaL1, oL, rlL, sK[0], sVt[0]);
        if (two) {
            tile_step(kt + 1, qtH, q0H, qaH0, qaH1, oH, rlH, sK[1], sVt[1]);
            if (kt + 1 <= qtL)
                tile_step(kt + 1, qtL, q0L, qaL0, qaL1, oL, rlL, sK[1], sVt[1]);
        }
        __syncthreads();
    }

    // epilogues (H then L)
#pragma unroll
    for (int e = 0; e < 2; ++e) {
        facc* o = e ? oL : oH;
        float* rowl = e ? rlL : rlH;
        const int q0 = e ? q0L : q0H;
        for (int r = 0; r < 4; ++r) {
            float l = rowl[r];
            l += __shfl_xor(l, 1);
            l += __shfl_xor(l, 2);
            l += __shfl_xor(l, 4);
            l += __shfl_xor(l, 8);
            const float inv = 1.0f / l;
            const int tt = q0 + w * 16 + quad * 4 + r;
            bf16* yrow = Y + ((size_t)b_ * T_ + tt) * C_ + h_ * HD_;
            for (int nb = 0; nb < 4; ++nb)
                yrow[nb * 16 + fr] = __float2bfloat16(o[nb][r] * inv);
        }
    }
}

extern "C" void kernel_launch(void* const* d_in, const int* in_sizes, int n_in,
                              void* d_out, int out_size, void* d_ws, size_t ws_size,
                              hipStream_t stream) {
    const float* x      = (const float*)d_in[0];
    const float* W_attn = (const float*)d_in[1];
    const float* b_attn = (const float*)d_in[2];
    const float* W_proj = (const float*)d_in[3];
    const float* b_proj = (const float*)d_in[4];
    float* out = (float*)d_out;

    const size_t per = (size_t)B_ * H_ * T_ * HD_;   // 6291456 bf16
    bf16* Q   = (bf16*)d_ws;
    bf16* K   = Q + per;
    bf16* Vt  = K + per;                 // transposed V [B,H,64,T]
    bf16* XbY = Vt + per;                // x-bf16, later attention output Y
    bf16* WaT = XbY + per;
    bf16* WpT = WaT + (size_t)N3_ * C_;

    static bool s_attr = false;
    if (!s_attr) {
        hipFuncSetAttribute((const void*)qkv64_kernel,
                            hipFuncAttributeMaxDynamicSharedMemorySize, 49152);
        hipFuncSetAttribute((const void*)proj_p_kernel,
                            hipFuncAttributeMaxDynamicSharedMemorySize, 57344);
        s_attr = true;
    }

    cvt_vec_kernel<<<dim3(XV + WABLK + 576), dim3(256), 0, stream>>>(
        x, XbY, W_attn, WaT, W_proj, WpT);
    qkv64_kernel<<<dim3(2304), dim3(256), 49152, stream>>>(
        XbY, WaT, b_attn, Q, K, Vt);
    flash_attn_kernel<<<dim3(768), dim3(256), 0, stream>>>(Q, K, Vt, XbY);
    proj_p_kernel<<<dim3(512), dim3(256), 57344, stream>>>(
        XbY, WpT, b_proj, out);
}